// Round 1
// baseline (13063.977 us; speedup 1.0000x reference)
//
#include <hip/hip_runtime.h>

// Problem constants
#define NROW   8192     // B*T
#define DMODEL 512
#define NHEAD  8
#define HDIM   64
#define TSEQ   1024
#define LAYERS 11
#define HIDDEN 1536

// ---------------------------------------------------------------------------
// RoPE cos/sin tables: cos[t][j] = cos(t * 10000^(-j/32)), j = 0..31
__global__ void rope_table_k(float* __restrict__ cosT, float* __restrict__ sinT) {
    int i = blockIdx.x * blockDim.x + threadIdx.x;   // 0..32767
    int t = i >> 5, j = i & 31;
    float freq = powf(10000.f, -(float)j * (1.f / 32.f));
    float ang = (float)t * freq;
    cosT[i] = cosf(ang);
    sinT[i] = sinf(ang);
}

// ---------------------------------------------------------------------------
// h[n,:] = embed[x[n],:]   (128 threads, float4)
__global__ void embed_gather_k(const int* __restrict__ x,
                               const float* __restrict__ embed,
                               float* __restrict__ h) {
    int n = blockIdx.x;
    int d = threadIdx.x;                     // 0..127
    const float4* e = (const float4*)(embed + (size_t)x[n] * DMODEL);
    float4* hp = (float4*)(h + (size_t)n * DMODEL);
    hp[d] = e[d];
}

// ---------------------------------------------------------------------------
// bgA[n,:] = bg_embed[prev(n),:]  prev = (t==0) ? 0 : x[n-1]
__global__ void bg_gather_k(const int* __restrict__ x,
                            const float* __restrict__ bge,
                            float* __restrict__ bgA) {
    int n = blockIdx.x;
    int t = n & (TSEQ - 1);
    int prev = (t == 0) ? 0 : x[n - 1];      // values < 1024 < NB=2048, no mod needed
    bgA[(size_t)n * 128 + threadIdx.x] = bge[(size_t)prev * 128 + threadIdx.x];
}

// ---------------------------------------------------------------------------
// RMSNorm: one wave per row of 512, 4 rows per block
__global__ __launch_bounds__(256) void rmsnorm_k(const float* __restrict__ in,
                                                 const float* __restrict__ w,
                                                 float* __restrict__ out) {
    int wv = threadIdx.x >> 6, lane = threadIdx.x & 63;
    int row = (blockIdx.x << 2) + wv;
    const float* rp = in + (size_t)row * DMODEL + lane * 8;
    float4 v0 = *(const float4*)(rp);
    float4 v1 = *(const float4*)(rp + 4);
    float ss = v0.x*v0.x + v0.y*v0.y + v0.z*v0.z + v0.w*v0.w
             + v1.x*v1.x + v1.y*v1.y + v1.z*v1.z + v1.w*v1.w;
#pragma unroll
    for (int off = 32; off; off >>= 1) ss += __shfl_xor(ss, off, 64);
    float sc = rsqrtf(ss * (1.f / DMODEL) + 1e-6f);
    const float* wp = w + lane * 8;
    float4 w0 = *(const float4*)(wp);
    float4 w1 = *(const float4*)(wp + 4);
    float* op = out + (size_t)row * DMODEL + lane * 8;
    float4 o0, o1;
    o0.x = v0.x * sc * w0.x; o0.y = v0.y * sc * w0.y;
    o0.z = v0.z * sc * w0.z; o0.w = v0.w * sc * w0.w;
    o1.x = v1.x * sc * w1.x; o1.y = v1.y * sc * w1.y;
    o1.z = v1.z * sc * w1.z; o1.w = v1.w * sc * w1.w;
    *(float4*)op = o0;
    *(float4*)(op + 4) = o1;
}

// ---------------------------------------------------------------------------
// RoPE in-place on q and k slices of qkv (B*T, 3*D)
// pairs (d, d+32) within each 64-dim head
__global__ __launch_bounds__(256) void rope_k(float* __restrict__ qkv,
                                              const float* __restrict__ cosT,
                                              const float* __restrict__ sinT) {
    int n = blockIdx.x;                  // row 0..8191
    int t = n & (TSEQ - 1);
    int h = threadIdx.x >> 5, d = threadIdx.x & 31;
    float c = cosT[t * 32 + d];
    float s = sinT[t * 32 + d];
    float* q = qkv + (size_t)n * (3 * DMODEL) + h * HDIM;
    float q1 = q[d], q2 = q[d + 32];
    q[d]      = q1 * c - q2 * s;
    q[d + 32] = q1 * s + q2 * c;
    float* k = q + DMODEL;
    float k1 = k[d], k2 = k[d + 32];
    k[d]      = k1 * c - k2 * s;
    k[d + 32] = k1 * s + k2 * c;
}

// ---------------------------------------------------------------------------
// GEMM: C[M,N] (op)= A[M,K] @ B[N,K]^T     (both K-contiguous, row-major)
// 128x128 tile, BK=8, 256 threads, 8x8 per thread.
// EPI: 0 = store, 1 = C += acc, 2 = C = relu(acc)^2
template<int EPI>
__global__ __launch_bounds__(256) void gemm_bt(const float* __restrict__ A,
                                               const float* __restrict__ B,
                                               float* __restrict__ C,
                                               int M, int N, int K) {
    __shared__ float As[8][128];
    __shared__ float Bs[8][128];
    const int bx = blockIdx.x;   // N tile
    const int by = blockIdx.y;   // M tile
    const int tid = threadIdx.x;
    const int r = tid >> 4;      // 0..15
    const int c = tid & 15;      // 0..15
    const int lrow = tid >> 1;            // 0..127
    const int lk = (tid & 1) * 4;         // 0 or 4

    float acc[8][8] = {{0.f}};

    const float* Aptr = A + ((size_t)(by * 128 + lrow)) * K + lk;
    const float* Bptr = B + ((size_t)(bx * 128 + lrow)) * K + lk;

    for (int k0 = 0; k0 < K; k0 += 8) {
        float4 av = *(const float4*)(Aptr + k0);
        float4 bv = *(const float4*)(Bptr + k0);
        __syncthreads();
        As[lk + 0][lrow] = av.x; As[lk + 1][lrow] = av.y;
        As[lk + 2][lrow] = av.z; As[lk + 3][lrow] = av.w;
        Bs[lk + 0][lrow] = bv.x; Bs[lk + 1][lrow] = bv.y;
        Bs[lk + 2][lrow] = bv.z; Bs[lk + 3][lrow] = bv.w;
        __syncthreads();
#pragma unroll
        for (int kk = 0; kk < 8; ++kk) {
            float a[8], b[8];
            *(float4*)&a[0] = *(const float4*)&As[kk][r * 8];
            *(float4*)&a[4] = *(const float4*)&As[kk][r * 8 + 4];
            *(float4*)&b[0] = *(const float4*)&Bs[kk][c * 8];
            *(float4*)&b[4] = *(const float4*)&Bs[kk][c * 8 + 4];
#pragma unroll
            for (int i = 0; i < 8; ++i)
#pragma unroll
                for (int j = 0; j < 8; ++j)
                    acc[i][j] += a[i] * b[j];
        }
    }

    float* Cbase = C + (size_t)(by * 128 + r * 8) * N + bx * 128 + c * 8;
#pragma unroll
    for (int i = 0; i < 8; ++i) {
        float* cp = Cbase + (size_t)i * N;
#pragma unroll
        for (int jj = 0; jj < 8; jj += 4) {
            float4 v;
            v.x = acc[i][jj]; v.y = acc[i][jj + 1];
            v.z = acc[i][jj + 2]; v.w = acc[i][jj + 3];
            if (EPI == 2) {
                v.x = fmaxf(v.x, 0.f); v.x *= v.x;
                v.y = fmaxf(v.y, 0.f); v.y *= v.y;
                v.z = fmaxf(v.z, 0.f); v.z *= v.z;
                v.w = fmaxf(v.w, 0.f); v.w *= v.w;
            } else if (EPI == 1) {
                float4 o = *(const float4*)(cp + jj);
                v.x += o.x; v.y += o.y; v.z += o.z; v.w += o.w;
            }
            *(float4*)(cp + jj) = v;
        }
    }
}

// ---------------------------------------------------------------------------
// Causal attention with self-weight subtraction, flash-style online softmax.
// One wave handles 4 consecutive query rows of one (b,h); 4 waves/block.
// Phase 1: lane = key index within 64-tile (scores). Phase 2: lane = d (PV).
__global__ __launch_bounds__(256) void attn_k(const float* __restrict__ qkv,
                                              float* __restrict__ out) {
    const int w = threadIdx.x >> 6, lane = threadIdx.x & 63;
    const int wid = blockIdx.x * 4 + w;            // 0..16383
    const int b = wid >> 11;                       // / (H*T/4)
    const int rem = wid & 2047;
    const int h = rem >> 8;                        // / (T/4)
    const int tq0 = (rem & 255) << 2;

    const size_t base = (size_t)b * TSEQ * (3 * DMODEL);
    const float* Q = qkv + base + h * HDIM;
    const float* Kp = qkv + base + DMODEL + h * HDIM;
    const float* Vp = qkv + base + 2 * DMODEL + h * HDIM;

    __shared__ float qs[4][4][64];
    __shared__ float ps[4][4][64];

#pragma unroll
    for (int r = 0; r < 4; ++r)
        qs[w][r][lane] = Q[(size_t)(tq0 + r) * (3 * DMODEL) + lane] * 0.125f;
    asm volatile("s_waitcnt lgkmcnt(0)" ::: "memory");

    float acc[4] = {0.f, 0.f, 0.f, 0.f};
    float m[4] = {-1e30f, -1e30f, -1e30f, -1e30f};
    float l[4] = {0.f, 0.f, 0.f, 0.f};
    float esf[4] = {0.f, 0.f, 0.f, 0.f};

    const int kend = tq0 + 4;
    for (int t0 = 0; t0 < kend; t0 += 64) {
        const int k = t0 + lane;
        const float* krow = Kp + (size_t)k * (3 * DMODEL);
        float s[4] = {0.f, 0.f, 0.f, 0.f};
#pragma unroll
        for (int d = 0; d < 64; d += 4) {
            float4 kv = *(const float4*)(krow + d);
#pragma unroll
            for (int r = 0; r < 4; ++r) {
                float4 qv = *(const float4*)&qs[w][r][d];
                s[r] += qv.x * kv.x + qv.y * kv.y + qv.z * kv.z + qv.w * kv.w;
            }
        }
#pragma unroll
        for (int r = 0; r < 4; ++r) {
            const int tq = tq0 + r;
            const bool valid = (k <= tq);
            float sm = valid ? s[r] : -1e30f;
            float tmax = sm;
#pragma unroll
            for (int off = 32; off; off >>= 1) tmax = fmaxf(tmax, __shfl_xor(tmax, off, 64));
            float mnew = fmaxf(m[r], tmax);
            float corr = __expf(m[r] - mnew);
            float p = valid ? __expf(sm - mnew) : 0.f;
            float psum = p;
#pragma unroll
            for (int off = 32; off; off >>= 1) psum += __shfl_xor(psum, off, 64);
            l[r] = l[r] * corr + psum;
            acc[r] *= corr;
            esf[r] = esf[r] * corr + ((k == tq) ? p : 0.f);
            m[r] = mnew;
            ps[w][r][lane] = p;
        }
        asm volatile("s_waitcnt lgkmcnt(0)" ::: "memory");
        const float* vrow = Vp + (size_t)t0 * (3 * DMODEL) + lane;
#pragma unroll 8
        for (int kk = 0; kk < 64; ++kk) {
            float v = vrow[(size_t)kk * (3 * DMODEL)];
#pragma unroll
            for (int r = 0; r < 4; ++r) acc[r] += ps[w][r][kk] * v;
        }
        asm volatile("s_waitcnt lgkmcnt(0)" ::: "memory");
    }

#pragma unroll
    for (int r = 0; r < 4; ++r) {
        float es = esf[r];
#pragma unroll
        for (int off = 32; off; off >>= 1) es += __shfl_xor(es, off, 64);
        float vq = Vp[(size_t)(tq0 + r) * (3 * DMODEL) + lane];
        float o = (acc[r] - es * vq) / l[r];
        out[(size_t)(b * TSEQ + tq0 + r) * DMODEL + h * HDIM + lane] = o;
    }
}

// ---------------------------------------------------------------------------
extern "C" void kernel_launch(void* const* d_in, const int* in_sizes, int n_in,
                              void* d_out, int out_size, void* d_ws, size_t ws_size,
                              hipStream_t stream) {
    const int*   x     = (const int*)d_in[0];
    const float* embed = (const float*)d_in[1];
    const float* Wqkv  = (const float*)d_in[2];
    const float* Wproj = (const float*)d_in[3];
    const float* n1w   = (const float*)d_in[4];
    const float* n2w   = (const float*)d_in[5];
    const float* Wfc1  = (const float*)d_in[6];
    const float* Wfc2  = (const float*)d_in[7];
    const float* normf = (const float*)d_in[8];
    const float* bge   = (const float*)d_in[9];
    const float* bgp   = (const float*)d_in[10];
    float* out = (float*)d_out;

    // workspace layout (floats): total ~38.9M floats = 155.5 MB
    float* ws   = (float*)d_ws;
    float* cosT = ws;                          // 32768
    float* sinT = cosT + 32768;                // 32768
    float* h    = sinT + 32768;                // 8192*512
    float* xn   = h    + (size_t)NROW * DMODEL;
    float* qkvb = xn   + (size_t)NROW * DMODEL;     // 8192*1536
    float* attn = qkvb + (size_t)NROW * 3 * DMODEL; // 8192*512
    float* u    = attn + (size_t)NROW * DMODEL;     // 8192*1536
    float* bgA  = u    + (size_t)NROW * HIDDEN;     // 8192*128

    rope_table_k<<<128, 256, 0, stream>>>(cosT, sinT);
    embed_gather_k<<<NROW, 128, 0, stream>>>(x, embed, h);

    for (int i = 0; i < LAYERS; ++i) {
        rmsnorm_k<<<NROW / 4, 256, 0, stream>>>(h, n1w + i * DMODEL, xn);
        gemm_bt<0><<<dim3(12, 64), 256, 0, stream>>>(
            xn, Wqkv + (size_t)i * 3 * DMODEL * DMODEL, qkvb, NROW, 3 * DMODEL, DMODEL);
        rope_k<<<NROW, 256, 0, stream>>>(qkvb, cosT, sinT);
        attn_k<<<4096, 256, 0, stream>>>(qkvb, attn);
        gemm_bt<1><<<dim3(4, 64), 256, 0, stream>>>(
            attn, Wproj + (size_t)i * DMODEL * DMODEL, h, NROW, DMODEL, DMODEL);
        rmsnorm_k<<<NROW / 4, 256, 0, stream>>>(h, n2w + i * DMODEL, xn);
        gemm_bt<2><<<dim3(12, 64), 256, 0, stream>>>(
            xn, Wfc1 + (size_t)i * HIDDEN * DMODEL, u, NROW, HIDDEN, DMODEL);
        gemm_bt<1><<<dim3(4, 64), 256, 0, stream>>>(
            u, Wfc2 + (size_t)i * DMODEL * HIDDEN, h, NROW, DMODEL, HIDDEN);
    }

    rmsnorm_k<<<NROW / 4, 256, 0, stream>>>(h, normf, xn);
    gemm_bt<0><<<dim3(8, 64), 256, 0, stream>>>(xn, embed, out, NROW, 1024, DMODEL);
    bg_gather_k<<<NROW, 128, 0, stream>>>(x, bge, bgA);
    gemm_bt<1><<<dim3(8, 64), 256, 0, stream>>>(bgA, bgp, out, NROW, 1024, 128);
}

// Round 2
// 8952.261 us; speedup vs baseline: 1.4593x; 1.4593x over previous
//
#include <hip/hip_runtime.h>

// Problem constants
#define NROW   8192     // B*T
#define DMODEL 512
#define NHEAD  8
#define HDIM   64
#define TSEQ   1024
#define LAYERS 11
#define HIDDEN 1536

typedef __bf16 bf16_t;
typedef bf16_t bf16x8 __attribute__((ext_vector_type(8)));
typedef float  f32x4  __attribute__((ext_vector_type(4)));

#define GLD16(gp, lp) __builtin_amdgcn_global_load_lds( \
    (const __attribute__((address_space(1))) void*)(gp), \
    (__attribute__((address_space(3))) void*)(lp), 16, 0, 0)

// ---------------------------------------------------------------------------
__global__ void rope_table_k(float* __restrict__ cosT, float* __restrict__ sinT) {
    int i = blockIdx.x * blockDim.x + threadIdx.x;   // 0..32767
    int t = i >> 5, j = i & 31;
    float freq = powf(10000.f, -(float)j * (1.f / 32.f));
    float ang = (float)t * freq;
    cosT[i] = cosf(ang);
    sinT[i] = sinf(ang);
}

// ---------------------------------------------------------------------------
__global__ void embed_gather_k(const int* __restrict__ x,
                               const float* __restrict__ embed,
                               float* __restrict__ h) {
    int n = blockIdx.x;
    int d = threadIdx.x;                     // 0..127
    const float4* e = (const float4*)(embed + (size_t)x[n] * DMODEL);
    float4* hp = (float4*)(h + (size_t)n * DMODEL);
    hp[d] = e[d];
}

// ---------------------------------------------------------------------------
__global__ void bg_gather_k(const int* __restrict__ x,
                            const float* __restrict__ bge,
                            bf16_t* __restrict__ bgA) {
    int n = blockIdx.x;
    int t = n & (TSEQ - 1);
    int prev = (t == 0) ? 0 : x[n - 1];      // < 1024 < NB=2048
    bgA[(size_t)n * 128 + threadIdx.x] = (bf16_t)bge[(size_t)prev * 128 + threadIdx.x];
}

// ---------------------------------------------------------------------------
// f32 -> bf16 elementwise, 8 per thread
__global__ void cvt_bf16_k(const float* __restrict__ in, bf16_t* __restrict__ out, int n8) {
    int i = blockIdx.x * blockDim.x + threadIdx.x;
    if (i >= n8) return;
    float4 a = ((const float4*)in)[2 * i];
    float4 b = ((const float4*)in)[2 * i + 1];
    bf16x8 o;
    o[0] = (bf16_t)a.x; o[1] = (bf16_t)a.y; o[2] = (bf16_t)a.z; o[3] = (bf16_t)a.w;
    o[4] = (bf16_t)b.x; o[5] = (bf16_t)b.y; o[6] = (bf16_t)b.z; o[7] = (bf16_t)b.w;
    ((bf16x8*)out)[i] = o;
}

// ---------------------------------------------------------------------------
// RMSNorm f32 in -> bf16 out. One wave per row, 4 rows per block.
__global__ __launch_bounds__(256) void rmsnorm_k(const float* __restrict__ in,
                                                 const float* __restrict__ w,
                                                 bf16_t* __restrict__ out) {
    int wv = threadIdx.x >> 6, lane = threadIdx.x & 63;
    int row = (blockIdx.x << 2) + wv;
    const float* rp = in + (size_t)row * DMODEL + lane * 8;
    float4 v0 = *(const float4*)(rp);
    float4 v1 = *(const float4*)(rp + 4);
    float ss = v0.x*v0.x + v0.y*v0.y + v0.z*v0.z + v0.w*v0.w
             + v1.x*v1.x + v1.y*v1.y + v1.z*v1.z + v1.w*v1.w;
#pragma unroll
    for (int off = 32; off; off >>= 1) ss += __shfl_xor(ss, off, 64);
    float sc = rsqrtf(ss * (1.f / DMODEL) + 1e-6f);
    const float* wp = w + lane * 8;
    float4 w0 = *(const float4*)(wp);
    float4 w1 = *(const float4*)(wp + 4);
    bf16x8 o;
    o[0] = (bf16_t)(v0.x * sc * w0.x); o[1] = (bf16_t)(v0.y * sc * w0.y);
    o[2] = (bf16_t)(v0.z * sc * w0.z); o[3] = (bf16_t)(v0.w * sc * w0.w);
    o[4] = (bf16_t)(v1.x * sc * w1.x); o[5] = (bf16_t)(v1.y * sc * w1.y);
    o[6] = (bf16_t)(v1.z * sc * w1.z); o[7] = (bf16_t)(v1.w * sc * w1.w);
    *(bf16x8*)(out + (size_t)row * DMODEL + lane * 8) = o;
}

// ---------------------------------------------------------------------------
// RoPE in-place on q and k slices of qkv f32 (B*T, 1536)
__global__ __launch_bounds__(256) void rope_k(float* __restrict__ qkv,
                                              const float* __restrict__ cosT,
                                              const float* __restrict__ sinT) {
    int n = blockIdx.x;
    int t = n & (TSEQ - 1);
    int h = threadIdx.x >> 5, d = threadIdx.x & 31;
    float c = cosT[t * 32 + d];
    float s = sinT[t * 32 + d];
    float* q = qkv + (size_t)n * (3 * DMODEL) + h * HDIM;
    float q1 = q[d], q2 = q[d + 32];
    q[d]      = q1 * c - q2 * s;
    q[d + 32] = q1 * s + q2 * c;
    float* k = q + DMODEL;
    float k1 = k[d], k2 = k[d + 32];
    k[d]      = k1 * c - k2 * s;
    k[d + 32] = k1 * s + k2 * c;
}

// ---------------------------------------------------------------------------
// bf16 MFMA GEMM (m97 structure): C[M,N] = A[M,K] @ B[N,K]^T
// 128x128 tile, BK=32, 256 threads (4 waves, each 64x64 = 4x4 frags of 16x16x32)
// EPI: 0 = f32 store, 1 = f32 +=, 2 = bf16 store of relu(acc)^2
template<int EPI>
__global__ __launch_bounds__(256) void gemm_mfma(const bf16_t* __restrict__ A,
                                                 const bf16_t* __restrict__ B,
                                                 float* __restrict__ Cf,
                                                 bf16_t* __restrict__ Cb,
                                                 int M, int N, int K) {
    __shared__ __align__(16) bf16_t As[128 * 32];
    __shared__ __align__(16) bf16_t Bs[128 * 32];
    const int tid = threadIdx.x;
    const int w = tid >> 6, lane = tid & 63;
    const int m0 = blockIdx.y * 128, n0 = blockIdx.x * 128;
    const int wr = (w >> 1) * 64, wc = (w & 1) * 64;
    const int fr = lane & 15, fq = lane >> 4;      // frag row sel / k-group

    f32x4 acc[4][4] = {};

    // stage one 128x32 A-tile and B-tile via global_load_lds (16B per lane)
    auto stage = [&](int k0) {
#pragma unroll
        for (int c = 0; c < 2; ++c) {
            int idx = c * 256 + tid;          // chunk id, 512 chunks of 16B per tile
            int row = idx >> 2, cs = idx & 3; // 4 chunks (32 bf16) per row
            const bf16_t* ga = A + (size_t)(m0 + row) * K + k0 + cs * 8;
            const bf16_t* gb = B + (size_t)(n0 + row) * K + k0 + cs * 8;
            // LDS dest: wave-uniform base; HW adds lane*16
            GLD16(ga, As + (size_t)(c * 256 + w * 64) * 8);
            GLD16(gb, Bs + (size_t)(c * 256 + w * 64) * 8);
        }
    };

    stage(0);
    int k0 = 0;
    while (true) {
        asm volatile("s_waitcnt vmcnt(0)" ::: "memory");
        __syncthreads();
        bf16x8 a[4], b[4];
        const bf16_t* ap = As + (size_t)(wr + fr) * 32 + fq * 8;
        const bf16_t* bp = Bs + (size_t)(wc + fr) * 32 + fq * 8;
#pragma unroll
        for (int i = 0; i < 4; ++i) {
            a[i] = *(const bf16x8*)(ap + i * 16 * 32);
            b[i] = *(const bf16x8*)(bp + i * 16 * 32);
        }
#pragma unroll
        for (int i = 0; i < 4; ++i)
#pragma unroll
            for (int j = 0; j < 4; ++j)
                acc[i][j] = __builtin_amdgcn_mfma_f32_16x16x32_bf16(a[i], b[j], acc[i][j], 0, 0, 0);
        k0 += 32;
        if (k0 >= K) break;
        __syncthreads();     // all waves done reading LDS before overwrite
        stage(k0);
    }

    // C/D layout: col = lane&15, row = (lane>>4)*4 + reg   [m89-verified]
#pragma unroll
    for (int i = 0; i < 4; ++i) {
        int row = m0 + wr + i * 16 + fq * 4;
#pragma unroll
        for (int j = 0; j < 4; ++j) {
            int col = n0 + wc + j * 16 + fr;
#pragma unroll
            for (int q = 0; q < 4; ++q) {
                float v = acc[i][j][q];
                size_t off = (size_t)(row + q) * N + col;
                if (EPI == 0)      Cf[off] = v;
                else if (EPI == 1) Cf[off] += v;
                else { v = fmaxf(v, 0.f); Cb[off] = (bf16_t)(v * v); }
            }
        }
    }
}

// ---------------------------------------------------------------------------
// Causal attention, flash-style. Block = 4 waves, one (b,h), 16 consecutive
// q rows (4 per wave). K (transposed) and V tiles staged in LDS, shared by
// all 4 waves. QK: lane=key, conflict-free KsT[d][lane] reads. PV: lane=d,
// conflict-free Vs[k][lane] reads. Row-sum & self-weight kept lane-local.
__global__ __launch_bounds__(256) void attn_k(const float* __restrict__ qkv,
                                              bf16_t* __restrict__ outb) {
    const int tid = threadIdx.x;
    const int w = tid >> 6, lane = tid & 63;
    const int bh = blockIdx.x >> 6;
    const int b = bh >> 3, h = bh & 7;
    int qb = blockIdx.x & 63;
    qb = (qb & 1) ? (63 - (qb >> 1)) : (qb >> 1);   // pair light+heavy blocks
    const int tq0b = qb << 4;
    const int tq0 = tq0b + w * 4;

    const size_t base = (size_t)b * TSEQ * 1536;
    const float* Q  = qkv + base + h * HDIM;
    const float* Kg = qkv + base + DMODEL + h * HDIM;
    const float* Vg = qkv + base + 2 * DMODEL + h * HDIM;

    __shared__ __align__(16) float KsT[64][68];   // [d][k]
    __shared__ __align__(16) float Vs[64][68];    // [k][d]
    __shared__ __align__(16) float qs[4][4][64];
    __shared__ __align__(16) float ps[4][4][64];

#pragma unroll
    for (int r = 0; r < 4; ++r)
        qs[w][r][lane] = Q[(size_t)(tq0 + r) * 1536 + lane] * 0.125f;

    float acc[4] = {0.f, 0.f, 0.f, 0.f};
    float m[4]   = {-1e30f, -1e30f, -1e30f, -1e30f};
    float pl[4]  = {0.f, 0.f, 0.f, 0.f};   // lane-local row-sum partial
    float esf[4] = {0.f, 0.f, 0.f, 0.f};   // lane-local self-weight partial

    const int kend = tq0b + 16;
    for (int t0 = 0; t0 < kend; t0 += 64) {
        __syncthreads();   // previous-iter LDS reads done (also covers qs)
        {
            const int r0 = tid >> 4;
            const int c4 = (tid & 15) * 4;
#pragma unroll
            for (int rr = 0; rr < 4; ++rr) {
                int row = r0 + rr * 16;
                const float* kp = Kg + (size_t)(t0 + row) * 1536 + c4;
                float4 kv = *(const float4*)kp;
                KsT[c4 + 0][row] = kv.x;
                KsT[c4 + 1][row] = kv.y;
                KsT[c4 + 2][row] = kv.z;
                KsT[c4 + 3][row] = kv.w;
                const float* vp = Vg + (size_t)(t0 + row) * 1536 + c4;
                *(float4*)&Vs[row][c4] = *(const float4*)vp;
            }
        }
        __syncthreads();

        // ---- QK: lane = key index
        const int k = t0 + lane;
        float s[4] = {0.f, 0.f, 0.f, 0.f};
#pragma unroll
        for (int d = 0; d < 64; d += 4) {
            float k0v = KsT[d + 0][lane];
            float k1v = KsT[d + 1][lane];
            float k2v = KsT[d + 2][lane];
            float k3v = KsT[d + 3][lane];
#pragma unroll
            for (int r = 0; r < 4; ++r) {
                float4 qv = *(const float4*)&qs[w][r][d];
                s[r] += qv.x * k0v + qv.y * k1v + qv.z * k2v + qv.w * k3v;
            }
        }
#pragma unroll
        for (int r = 0; r < 4; ++r) {
            const int tq = tq0 + r;
            const bool valid = (k <= tq);
            float sm = valid ? s[r] : -1e30f;
            float tmax = sm;
#pragma unroll
            for (int off = 32; off; off >>= 1) tmax = fmaxf(tmax, __shfl_xor(tmax, off, 64));
            float mnew = fmaxf(m[r], tmax);
            float corr = __expf(m[r] - mnew);
            float p = valid ? __expf(sm - mnew) : 0.f;
            pl[r]  = pl[r] * corr + p;
            acc[r] *= corr;
            esf[r] = esf[r] * corr + ((k == tq) ? p : 0.f);
            m[r] = mnew;
            ps[w][r][lane] = p;
        }
        asm volatile("s_waitcnt lgkmcnt(0)" ::: "memory");

        // ---- PV: lane = d
#pragma unroll
        for (int kk = 0; kk < 64; kk += 4) {
            float v0 = Vs[kk + 0][lane];
            float v1 = Vs[kk + 1][lane];
            float v2 = Vs[kk + 2][lane];
            float v3 = Vs[kk + 3][lane];
#pragma unroll
            for (int r = 0; r < 4; ++r) {
                float4 pv = *(const float4*)&ps[w][r][kk];
                acc[r] += pv.x * v0 + pv.y * v1 + pv.z * v2 + pv.w * v3;
            }
        }
    }

#pragma unroll
    for (int r = 0; r < 4; ++r) {
        float l = pl[r], es = esf[r];
#pragma unroll
        for (int off = 32; off; off >>= 1) {
            l  += __shfl_xor(l, off, 64);
            es += __shfl_xor(es, off, 64);
        }
        float vq = Vg[(size_t)(tq0 + r) * 1536 + lane];
        float o = (acc[r] - es * vq) / l;
        outb[(size_t)(b * TSEQ + tq0 + r) * DMODEL + h * HDIM + lane] = (bf16_t)o;
    }
}

// ---------------------------------------------------------------------------
static inline void cvt(const float* in, bf16_t* out, size_t n, hipStream_t s) {
    int n8 = (int)(n / 8);
    cvt_bf16_k<<<(n8 + 255) / 256, 256, 0, s>>>(in, out, n8);
}

extern "C" void kernel_launch(void* const* d_in, const int* in_sizes, int n_in,
                              void* d_out, int out_size, void* d_ws, size_t ws_size,
                              hipStream_t stream) {
    const int*   x     = (const int*)d_in[0];
    const float* embed = (const float*)d_in[1];
    const float* Wqkv  = (const float*)d_in[2];
    const float* Wproj = (const float*)d_in[3];
    const float* n1w   = (const float*)d_in[4];
    const float* n2w   = (const float*)d_in[5];
    const float* Wfc1  = (const float*)d_in[6];
    const float* Wfc2  = (const float*)d_in[7];
    const float* normf = (const float*)d_in[8];
    const float* bge   = (const float*)d_in[9];
    const float* bgp   = (const float*)d_in[10];
    float* out = (float*)d_out;

    // workspace layout (~138 MB)
    float* ws   = (float*)d_ws;
    float* cosT = ws;                            // 32768
    float* sinT = cosT + 32768;                  // 32768
    float* h    = sinT + 32768;                  // 8192*512 f32
    float* qkv  = h + (size_t)NROW * DMODEL;     // 8192*1536 f32 (u_bf aliases this)
    bf16_t* xn   = (bf16_t*)(qkv + (size_t)NROW * 3 * DMODEL);
    bf16_t* atb  = xn  + (size_t)NROW * DMODEL;  // attn out bf16
    bf16_t* bga  = atb + (size_t)NROW * DMODEL;  // 8192*128 bf16
    bf16_t* wqb  = bga + (size_t)NROW * 128;
    bf16_t* wpb  = wqb + (size_t)LAYERS * 3 * DMODEL * DMODEL;
    bf16_t* w1b  = wpb + (size_t)LAYERS * DMODEL * DMODEL;
    bf16_t* w2b  = w1b + (size_t)LAYERS * HIDDEN * DMODEL;
    bf16_t* embb = w2b + (size_t)LAYERS * DMODEL * HIDDEN;
    bf16_t* bgpb = embb + (size_t)1024 * DMODEL;
    bf16_t* ub   = (bf16_t*)qkv;                 // alias: qkv dead when fc1 runs

    rope_table_k<<<128, 256, 0, stream>>>(cosT, sinT);
    embed_gather_k<<<NROW, 128, 0, stream>>>(x, embed, h);
    bg_gather_k<<<NROW, 128, 0, stream>>>(x, bge, bga);

    cvt(Wqkv,  wqb,  (size_t)LAYERS * 3 * DMODEL * DMODEL, stream);
    cvt(Wproj, wpb,  (size_t)LAYERS * DMODEL * DMODEL, stream);
    cvt(Wfc1,  w1b,  (size_t)LAYERS * HIDDEN * DMODEL, stream);
    cvt(Wfc2,  w2b,  (size_t)LAYERS * DMODEL * HIDDEN, stream);
    cvt(embed, embb, (size_t)1024 * DMODEL, stream);
    cvt(bgp,   bgpb, (size_t)1024 * 128, stream);

    for (int i = 0; i < LAYERS; ++i) {
        rmsnorm_k<<<NROW / 4, 256, 0, stream>>>(h, n1w + i * DMODEL, xn);
        gemm_mfma<0><<<dim3(12, 64), 256, 0, stream>>>(
            xn, wqb + (size_t)i * 3 * DMODEL * DMODEL, qkv, nullptr, NROW, 3 * DMODEL, DMODEL);
        rope_k<<<NROW, 256, 0, stream>>>(qkv, cosT, sinT);
        attn_k<<<4096, 256, 0, stream>>>(qkv, atb);
        gemm_mfma<1><<<dim3(4, 64), 256, 0, stream>>>(
            atb, wpb + (size_t)i * DMODEL * DMODEL, h, nullptr, NROW, DMODEL, DMODEL);
        rmsnorm_k<<<NROW / 4, 256, 0, stream>>>(h, n2w + i * DMODEL, xn);
        gemm_mfma<2><<<dim3(12, 64), 256, 0, stream>>>(
            xn, w1b + (size_t)i * HIDDEN * DMODEL, nullptr, ub, NROW, HIDDEN, DMODEL);
        gemm_mfma<1><<<dim3(4, 64), 256, 0, stream>>>(
            ub, w2b + (size_t)i * DMODEL * HIDDEN, h, nullptr, NROW, DMODEL, HIDDEN);
    }

    rmsnorm_k<<<NROW / 4, 256, 0, stream>>>(h, normf, xn);
    gemm_mfma<0><<<dim3(8, 64), 256, 0, stream>>>(xn, embb, out, nullptr, NROW, 1024, DMODEL);
    gemm_mfma<1><<<dim3(8, 64), 256, 0, stream>>>(bga, bgpb, out, nullptr, NROW, 1024, 128);
}

// Round 4
// 2250.793 us; speedup vs baseline: 5.8042x; 3.9774x over previous
//
#include <hip/hip_runtime.h>

// Problem constants
#define NROW   8192     // B*T
#define DMODEL 512
#define TSEQ   1024
#define LAYERS 11
#define HIDDEN 1536

typedef __bf16 bf16_t;
typedef bf16_t bf16x8 __attribute__((ext_vector_type(8)));
typedef bf16_t bf16x4 __attribute__((ext_vector_type(4)));
typedef float  f32x4  __attribute__((ext_vector_type(4)));
typedef unsigned int u32;
typedef u32 u32x4 __attribute__((ext_vector_type(4)));

#define GLD16(gp, lp) __builtin_amdgcn_global_load_lds( \
    (const __attribute__((address_space(1))) void*)(gp), \
    (__attribute__((address_space(3))) void*)(lp), 16, 0, 0)

// ---------------------------------------------------------------------------
__global__ void rope_table_k(float* __restrict__ cosT, float* __restrict__ sinT) {
    int i = blockIdx.x * blockDim.x + threadIdx.x;   // 0..32767
    int t = i >> 5, j = i & 31;
    float freq = powf(10000.f, -(float)j * (1.f / 32.f));
    float ang = (float)t * freq;
    cosT[i] = cosf(ang);
    sinT[i] = sinf(ang);
}

// ---------------------------------------------------------------------------
__global__ void embed_gather_k(const int* __restrict__ x,
                               const float* __restrict__ embed,
                               float* __restrict__ h) {
    int n = blockIdx.x;
    int d = threadIdx.x;                     // 0..127
    const float4* e = (const float4*)(embed + (size_t)x[n] * DMODEL);
    float4* hp = (float4*)(h + (size_t)n * DMODEL);
    hp[d] = e[d];
}

// ---------------------------------------------------------------------------
__global__ void bg_gather_k(const int* __restrict__ x,
                            const float* __restrict__ bge,
                            bf16_t* __restrict__ bgA) {
    int n = blockIdx.x;
    int t = n & (TSEQ - 1);
    int prev = (t == 0) ? 0 : x[n - 1];      // < 1024 < NB=2048
    bgA[(size_t)n * 128 + threadIdx.x] = (bf16_t)bge[(size_t)prev * 128 + threadIdx.x];
}

// ---------------------------------------------------------------------------
__global__ void cvt_bf16_k(const float* __restrict__ in, bf16_t* __restrict__ out, int n8) {
    int i = blockIdx.x * blockDim.x + threadIdx.x;
    if (i >= n8) return;
    float4 a = ((const float4*)in)[2 * i];
    float4 b = ((const float4*)in)[2 * i + 1];
    bf16x8 o;
    o[0] = (bf16_t)a.x; o[1] = (bf16_t)a.y; o[2] = (bf16_t)a.z; o[3] = (bf16_t)a.w;
    o[4] = (bf16_t)b.x; o[5] = (bf16_t)b.y; o[6] = (bf16_t)b.z; o[7] = (bf16_t)b.w;
    ((bf16x8*)out)[i] = o;
}

// ---------------------------------------------------------------------------
// RMSNorm f32 in -> bf16 out. One wave per row, 4 rows per block.
__global__ __launch_bounds__(256) void rmsnorm_k(const float* __restrict__ in,
                                                 const float* __restrict__ w,
                                                 bf16_t* __restrict__ out) {
    int wv = threadIdx.x >> 6, lane = threadIdx.x & 63;
    int row = (blockIdx.x << 2) + wv;
    const float* rp = in + (size_t)row * DMODEL + lane * 8;
    float4 v0 = *(const float4*)(rp);
    float4 v1 = *(const float4*)(rp + 4);
    float ss = v0.x*v0.x + v0.y*v0.y + v0.z*v0.z + v0.w*v0.w
             + v1.x*v1.x + v1.y*v1.y + v1.z*v1.z + v1.w*v1.w;
#pragma unroll
    for (int off = 32; off; off >>= 1) ss += __shfl_xor(ss, off, 64);
    float sc = rsqrtf(ss * (1.f / DMODEL) + 1e-6f);
    const float* wp = w + lane * 8;
    float4 w0 = *(const float4*)(wp);
    float4 w1 = *(const float4*)(wp + 4);
    bf16x8 o;
    o[0] = (bf16_t)(v0.x * sc * w0.x); o[1] = (bf16_t)(v0.y * sc * w0.y);
    o[2] = (bf16_t)(v0.z * sc * w0.z); o[3] = (bf16_t)(v0.w * sc * w0.w);
    o[4] = (bf16_t)(v1.x * sc * w1.x); o[5] = (bf16_t)(v1.y * sc * w1.y);
    o[6] = (bf16_t)(v1.z * sc * w1.z); o[7] = (bf16_t)(v1.w * sc * w1.w);
    *(bf16x8*)(out + (size_t)row * DMODEL + lane * 8) = o;
}

// ---------------------------------------------------------------------------
// RoPE in-place on bf16 qkv (B*T, 1536): q and k slices, pairs (d, d+32)
__global__ __launch_bounds__(256) void rope_bf16_k(bf16_t* __restrict__ qkv,
                                                   const float* __restrict__ cosT,
                                                   const float* __restrict__ sinT) {
    int n = blockIdx.x;
    int t = n & (TSEQ - 1);
    int hh = threadIdx.x >> 5, d = threadIdx.x & 31;
    float c = cosT[t * 32 + d];
    float s = sinT[t * 32 + d];
    bf16_t* q = qkv + (size_t)n * 1536 + hh * 64;
    float q1 = (float)q[d], q2 = (float)q[d + 32];
    q[d]      = (bf16_t)(q1 * c - q2 * s);
    q[d + 32] = (bf16_t)(q1 * s + q2 * c);
    bf16_t* k = q + 512;
    float k1 = (float)k[d], k2 = (float)k[d + 32];
    k[d]      = (bf16_t)(k1 * c - k2 * s);
    k[d + 32] = (bf16_t)(k1 * s + k2 * c);
}

// ---------------------------------------------------------------------------
// bf16 MFMA GEMM (m97 structure): C[M,N] = A[M,K] @ B[N,K]^T
// EPI: 0 = f32 store, 1 = f32 +=, 2 = bf16 relu(acc)^2, 3 = bf16 store
template<int EPI>
__global__ __launch_bounds__(256) void gemm_mfma(const bf16_t* __restrict__ A,
                                                 const bf16_t* __restrict__ B,
                                                 float* __restrict__ Cf,
                                                 bf16_t* __restrict__ Cb,
                                                 int M, int N, int K) {
    __shared__ __align__(16) bf16_t As[128 * 32];
    __shared__ __align__(16) bf16_t Bs[128 * 32];
    const int tid = threadIdx.x;
    const int w = tid >> 6, lane = tid & 63;
    const int m0 = blockIdx.y * 128, n0 = blockIdx.x * 128;
    const int wr = (w >> 1) * 64, wc = (w & 1) * 64;
    const int fr = lane & 15, fq = lane >> 4;

    f32x4 acc[4][4] = {};

    auto stage = [&](int k0) {
#pragma unroll
        for (int c = 0; c < 2; ++c) {
            int idx = c * 256 + tid;
            int row = idx >> 2, cs = idx & 3;
            const bf16_t* ga = A + (size_t)(m0 + row) * K + k0 + cs * 8;
            const bf16_t* gb = B + (size_t)(n0 + row) * K + k0 + cs * 8;
            GLD16(ga, As + (size_t)(c * 256 + w * 64) * 8);
            GLD16(gb, Bs + (size_t)(c * 256 + w * 64) * 8);
        }
    };

    stage(0);
    int k0 = 0;
    while (true) {
        asm volatile("s_waitcnt vmcnt(0)" ::: "memory");
        __syncthreads();
        bf16x8 a[4], b[4];
        const bf16_t* ap = As + (size_t)(wr + fr) * 32 + fq * 8;
        const bf16_t* bp = Bs + (size_t)(wc + fr) * 32 + fq * 8;
#pragma unroll
        for (int i = 0; i < 4; ++i) {
            a[i] = *(const bf16x8*)(ap + i * 16 * 32);
            b[i] = *(const bf16x8*)(bp + i * 16 * 32);
        }
#pragma unroll
        for (int i = 0; i < 4; ++i)
#pragma unroll
            for (int j = 0; j < 4; ++j)
                acc[i][j] = __builtin_amdgcn_mfma_f32_16x16x32_bf16(a[i], b[j], acc[i][j], 0, 0, 0);
        k0 += 32;
        if (k0 >= K) break;
        __syncthreads();
        stage(k0);
    }

#pragma unroll
    for (int i = 0; i < 4; ++i) {
        int row = m0 + wr + i * 16 + fq * 4;
#pragma unroll
        for (int j = 0; j < 4; ++j) {
            int col = n0 + wc + j * 16 + fr;
#pragma unroll
            for (int q = 0; q < 4; ++q) {
                float v = acc[i][j][q];
                size_t off = (size_t)(row + q) * N + col;
                if (EPI == 0)      Cf[off] = v;
                else if (EPI == 1) Cf[off] += v;
                else if (EPI == 2) { v = fmaxf(v, 0.f); Cb[off] = (bf16_t)(v * v); }
                else               Cb[off] = (bf16_t)v;
            }
        }
    }
}

// ---------------------------------------------------------------------------
// MFMA flash attention, validated-mechanisms-only build.
// Block = 4 waves = 64 q-rows of one (b,h); KV tile 64.
//   QK^T swapped:  S^T = K · Q^T  (16x16x32, K from LDS w/ chunk-XOR swizzle)
//   PV   swapped:  O^T = V^T · P^T (16x16x32, V^T built by register 4x4
//                  transpose into pad-72 LDS rows; P^T frags via 16 shfl/tile)
// Both C-layouts land with q = lane&15, matching the per-lane softmax state:
// no cross-lane rescale or epilogue gathers needed.
__global__ __launch_bounds__(256) void attn_mfma_k(const bf16_t* __restrict__ qkvb,
                                                   bf16_t* __restrict__ outb) {
    __shared__ __align__(16) bf16_t Ks[64 * 64];     // [key][slot^] chunk-XOR
    __shared__ __align__(16) bf16_t VsT[64 * 72];    // [d][key], rows padded to 72

    const int tid = threadIdx.x;
    const int w  = tid >> 6;
    const int ln = tid & 63;
    const int lr = ln & 15;       // q-lane
    const int lg = ln >> 4;       // lane group

    // XCD-chunked swizzle: 8 consecutive bh per XCD
    int raw = blockIdx.x;
    int swz = (raw & 7) * 128 + (raw >> 3);
    const int bh = swz >> 4;
    const int b = bh >> 3, h = bh & 7;
    int qbr = swz & 15;
    const int qb  = (qbr & 1) ? (15 - (qbr >> 1)) : (qbr >> 1);  // pair light+heavy
    const int tq0b = qb << 6;
    const int tq0  = tq0b + w * 16;

    const bf16_t* Qg = qkvb + (size_t)b * TSEQ * 1536 + h * 64;
    const bf16_t* Kg = Qg + 512;
    const bf16_t* Vg = Qg + 1024;

    // Q regs (B-operand of swapped QK): lane holds Q[tq0+lr][s*32 + lg*8 + j]
    bf16x8 qreg[2];
    {
        const bf16_t* qp = Qg + (size_t)(tq0 + lr) * 1536 + lg * 8;
        qreg[0] = *(const bf16x8*)qp;
        qreg[1] = *(const bf16x8*)(qp + 32);
#pragma unroll
        for (int j = 0; j < 8; ++j) {
            qreg[0][j] = (bf16_t)((float)qreg[0][j] * 0.125f);
            qreg[1][j] = (bf16_t)((float)qreg[1][j] * 0.125f);
        }
    }

    // V staging micro-tile assignment: keys mk*4..+3, d md*4..+3
    const int mk = tid >> 4;      // 0..15
    const int md = tid & 15;      // 0..15

    f32x4 accO[4] = {};           // accO[dblk][r] = O[q=tq0+lr][d=dblk*16+lg*4+r]
    float mrun = -1e30f, pl = 0.f, esf = 0.f;
    const int qrow = tq0 + lr;
    const int src0 = lr + 32 * (lg & 1);   // P source lanes: src0, src0+16
    const int fsel = lg >> 1;

    for (int t0 = 0; t0 <= tq0b; t0 += 64) {
        __syncthreads();          // prev-tile LDS reads done before overwrite

        // ---- K stage: GLD16, linear rows + chunk-XOR-swizzled source
#pragma unroll
        for (int ii = 0; ii < 2; ++ii) {
            const int i = w * 2 + ii;
            int key = i * 8 + (ln >> 3);
            int dc  = (ln & 7) ^ (ln >> 3);
            GLD16(Kg + (size_t)(t0 + key) * 1536 + dc * 8, Ks + i * 512);
        }
        // ---- V stage: global b64 reads, register 4x4 transpose, ds_write_b64
        {
            bf16x4 rv[4];
#pragma unroll
            for (int i = 0; i < 4; ++i)
                rv[i] = *(const bf16x4*)(Vg + (size_t)(t0 + mk * 4 + i) * 1536 + md * 4);
#pragma unroll
            for (int j = 0; j < 4; ++j) {
                bf16x4 wv;
                wv[0] = rv[0][j]; wv[1] = rv[1][j]; wv[2] = rv[2][j]; wv[3] = rv[3][j];
                *(bf16x4*)(VsT + (size_t)(md * 4 + j) * 72 + mk * 4) = wv;
            }
        }
        __syncthreads();          // drains vmcnt (GLD16) + lgkmcnt (ds_write)

        // ---- QK^T (swapped): S^T[key][q], A = K frags from swizzled LDS
        f32x4 sq[4] = {};
#pragma unroll
        for (int kr = 0; kr < 4; ++kr) {
            int key = kr * 16 + lr;
#pragma unroll
            for (int s = 0; s < 2; ++s) {
                int chunk = key * 8 + ((s * 4 + lg) ^ (key & 7));
                bf16x8 kf = *(const bf16x8*)(Ks + chunk * 8);
                sq[kr] = __builtin_amdgcn_mfma_f32_16x16x32_bf16(kf, qreg[s], sq[kr], 0, 0, 0);
            }
        }

        // ---- online softmax; lane's q = qrow, 16 lane-local keys
        float p[4][4];
        float tm = -1e30f;
#pragma unroll
        for (int f = 0; f < 4; ++f)
#pragma unroll
            for (int r = 0; r < 4; ++r) {
                int key = t0 + f * 16 + lg * 4 + r;
                float sv = (key <= qrow) ? sq[f][r] : -1e30f;
                p[f][r] = sv;
                tm = fmaxf(tm, sv);
            }
        tm = fmaxf(tm, __shfl_xor(tm, 16, 64));
        tm = fmaxf(tm, __shfl_xor(tm, 32, 64));
        float mnew = fmaxf(mrun, tm);
        float corr = __expf(mrun - mnew);
        mrun = mnew;
        float psum = 0.f, pd = 0.f;
#pragma unroll
        for (int f = 0; f < 4; ++f)
#pragma unroll
            for (int r = 0; r < 4; ++r) {
                float e = __expf(p[f][r] - mnew);   // masked: exp(-huge)=0
                p[f][r] = e;
                psum += e;
                int key = t0 + f * 16 + lg * 4 + r;
                pd = (key == qrow) ? e : pd;
            }
        pl  = pl  * corr + psum;
        esf = esf * corr + pd;
#pragma unroll
        for (int dblk = 0; dblk < 4; ++dblk)
#pragma unroll
            for (int r = 0; r < 4; ++r) accO[dblk][r] *= corr;   // q = lr aligned

        // ---- pack P rows to bf16 pairs (uniform register indices only)
        u32 plo[4], phi[4];
#pragma unroll
        for (int f = 0; f < 4; ++f) {
            bf16x4 t;
            t[0] = (bf16_t)p[f][0]; t[1] = (bf16_t)p[f][1];
            t[2] = (bf16_t)p[f][2]; t[3] = (bf16_t)p[f][3];
            uint2 pr = __builtin_bit_cast(uint2, t);
            plo[f] = pr.x; phi[f] = pr.y;
        }

        // ---- PV (swapped): O^T = V^T · P^T, 16x16x32
        // B-frag: shuffle BOTH f-candidates (uniform reg index), select by
        // receiver's fsel = lg>>1 afterwards.
#pragma unroll
        for (int s = 0; s < 2; ++s) {
            u32 a0 = (u32)__shfl((int)plo[s * 2],     src0,      64);
            u32 a1 = (u32)__shfl((int)phi[s * 2],     src0,      64);
            u32 a2 = (u32)__shfl((int)plo[s * 2],     src0 + 16, 64);
            u32 a3 = (u32)__shfl((int)phi[s * 2],     src0 + 16, 64);
            u32 c0 = (u32)__shfl((int)plo[s * 2 + 1], src0,      64);
            u32 c1 = (u32)__shfl((int)phi[s * 2 + 1], src0,      64);
            u32 c2 = (u32)__shfl((int)plo[s * 2 + 1], src0 + 16, 64);
            u32 c3 = (u32)__shfl((int)phi[s * 2 + 1], src0 + 16, 64);
            u32x4 bw;
            bw[0] = fsel ? c0 : a0;
            bw[1] = fsel ? c1 : a1;
            bw[2] = fsel ? c2 : a2;
            bw[3] = fsel ? c3 : a3;
            bf16x8 bfrag = __builtin_bit_cast(bf16x8, bw);
#pragma unroll
            for (int dblk = 0; dblk < 4; ++dblk) {
                bf16x8 av = *(const bf16x8*)(VsT + (size_t)(dblk * 16 + lr) * 72 + s * 32 + lg * 8);
                accO[dblk] = __builtin_amdgcn_mfma_f32_16x16x32_bf16(av, bfrag, accO[dblk], 0, 0, 0);
            }
        }
    }

    // ---- epilogue: reduce l and self-weight over lane groups, subtract, store
    pl  += __shfl_xor(pl, 16, 64);  pl  += __shfl_xor(pl, 32, 64);
    esf += __shfl_xor(esf, 16, 64); esf += __shfl_xor(esf, 32, 64);
    float rin = 1.0f / pl;
    const bf16_t* vqp = Vg + (size_t)qrow * 1536;
    bf16_t* op = outb + (size_t)(b * TSEQ + qrow) * DMODEL + h * 64;
#pragma unroll
    for (int dblk = 0; dblk < 4; ++dblk) {
        bf16x4 vq = *(const bf16x4*)(vqp + dblk * 16 + lg * 4);
        bf16x4 o4;
#pragma unroll
        for (int r = 0; r < 4; ++r)
            o4[r] = (bf16_t)((accO[dblk][r] - esf * (float)vq[r]) * rin);
        *(bf16x4*)(op + dblk * 16 + lg * 4) = o4;
    }
}

// ---------------------------------------------------------------------------
static inline void cvt(const float* in, bf16_t* out, size_t n, hipStream_t s) {
    int n8 = (int)(n / 8);
    cvt_bf16_k<<<(n8 + 255) / 256, 256, 0, s>>>(in, out, n8);
}

extern "C" void kernel_launch(void* const* d_in, const int* in_sizes, int n_in,
                              void* d_out, int out_size, void* d_ws, size_t ws_size,
                              hipStream_t stream) {
    const int*   x     = (const int*)d_in[0];
    const float* embed = (const float*)d_in[1];
    const float* Wqkv  = (const float*)d_in[2];
    const float* Wproj = (const float*)d_in[3];
    const float* n1w   = (const float*)d_in[4];
    const float* n2w   = (const float*)d_in[5];
    const float* Wfc1  = (const float*)d_in[6];
    const float* Wfc2  = (const float*)d_in[7];
    const float* normf = (const float*)d_in[8];
    const float* bge   = (const float*)d_in[9];
    const float* bgp   = (const float*)d_in[10];
    float* out = (float*)d_out;

    // workspace layout (~118 MB)
    float* ws   = (float*)d_ws;
    float* cosT = ws;                            // 32768
    float* sinT = cosT + 32768;                  // 32768
    float* h    = sinT + 32768;                  // 8192*512 f32
    bf16_t* qkvb = (bf16_t*)(h + (size_t)NROW * DMODEL);  // 8192*1536 bf16
    bf16_t* ub   = qkvb;                         // alias: qkvb dead when fc1 runs
    bf16_t* xn   = qkvb + (size_t)NROW * 1536;
    bf16_t* atb  = xn  + (size_t)NROW * DMODEL;
    bf16_t* bga  = atb + (size_t)NROW * DMODEL;  // 8192*128
    bf16_t* wqb  = bga + (size_t)NROW * 128;
    bf16_t* wpb  = wqb + (size_t)LAYERS * 3 * DMODEL * DMODEL;
    bf16_t* w1b  = wpb + (size_t)LAYERS * DMODEL * DMODEL;
    bf16_t* w2b  = w1b + (size_t)LAYERS * HIDDEN * DMODEL;
    bf16_t* embb = w2b + (size_t)LAYERS * DMODEL * HIDDEN;
    bf16_t* bgpb = embb + (size_t)1024 * DMODEL;

    rope_table_k<<<128, 256, 0, stream>>>(cosT, sinT);
    embed_gather_k<<<NROW, 128, 0, stream>>>(x, embed, h);
    bg_gather_k<<<NROW, 128, 0, stream>>>(x, bge, bga);

    cvt(Wqkv,  wqb,  (size_t)LAYERS * 3 * DMODEL * DMODEL, stream);
    cvt(Wproj, wpb,  (size_t)LAYERS * DMODEL * DMODEL, stream);
    cvt(Wfc1,  w1b,  (size_t)LAYERS * HIDDEN * DMODEL, stream);
    cvt(Wfc2,  w2b,  (size_t)LAYERS * DMODEL * HIDDEN, stream);
    cvt(embed, embb, (size_t)1024 * DMODEL, stream);
    cvt(bgp,   bgpb, (size_t)1024 * 128, stream);

    for (int i = 0; i < LAYERS; ++i) {
        rmsnorm_k<<<NROW / 4, 256, 0, stream>>>(h, n1w + i * DMODEL, xn);
        gemm_mfma<3><<<dim3(12, 64), 256, 0, stream>>>(
            xn, wqb + (size_t)i * 3 * DMODEL * DMODEL, nullptr, qkvb, NROW, 3 * DMODEL, DMODEL);
        rope_bf16_k<<<NROW, 256, 0, stream>>>(qkvb, cosT, sinT);
        attn_mfma_k<<<1024, 256, 0, stream>>>(qkvb, atb);
        gemm_mfma<1><<<dim3(4, 64), 256, 0, stream>>>(
            atb, wpb + (size_t)i * DMODEL * DMODEL, h, nullptr, NROW, DMODEL, DMODEL);
        rmsnorm_k<<<NROW / 4, 256, 0, stream>>>(h, n2w + i * DMODEL, xn);
        gemm_mfma<2><<<dim3(12, 64), 256, 0, stream>>>(
            xn, w1b + (size_t)i * HIDDEN * DMODEL, nullptr, ub, NROW, HIDDEN, DMODEL);
        gemm_mfma<1><<<dim3(4, 64), 256, 0, stream>>>(
            ub, w2b + (size_t)i * DMODEL * HIDDEN, h, nullptr, NROW, DMODEL, HIDDEN);
    }

    rmsnorm_k<<<NROW / 4, 256, 0, stream>>>(h, normf, xn);
    gemm_mfma<0><<<dim3(8, 64), 256, 0, stream>>>(xn, embb, out, nullptr, NROW, 1024, DMODEL);
    gemm_mfma<1><<<dim3(8, 64), 256, 0, stream>>>(bga, bgpb, out, nullptr, NROW, 1024, 128);
}

// Round 5
// 1962.442 us; speedup vs baseline: 6.6570x; 1.1469x over previous
//
#include <hip/hip_runtime.h>

// Problem constants
#define NROW   8192     // B*T
#define DMODEL 512
#define TSEQ   1024
#define LAYERS 11
#define HIDDEN 1536

typedef __bf16 bf16_t;
typedef bf16_t bf16x8 __attribute__((ext_vector_type(8)));
typedef bf16_t bf16x4 __attribute__((ext_vector_type(4)));
typedef float  f32x4  __attribute__((ext_vector_type(4)));
typedef unsigned int u32;
typedef u32 u32x4 __attribute__((ext_vector_type(4)));

#define GLD16(gp, lp) __builtin_amdgcn_global_load_lds( \
    (const __attribute__((address_space(1))) void*)(gp), \
    (__attribute__((address_space(3))) void*)(lp), 16, 0, 0)

// ---------------------------------------------------------------------------
__global__ void rope_table_k(float* __restrict__ cosT, float* __restrict__ sinT) {
    int i = blockIdx.x * blockDim.x + threadIdx.x;   // 0..32767
    int t = i >> 5, j = i & 31;
    float freq = powf(10000.f, -(float)j * (1.f / 32.f));
    float ang = (float)t * freq;
    cosT[i] = cosf(ang);
    sinT[i] = sinf(ang);
}

// ---------------------------------------------------------------------------
__global__ void embed_gather_k(const int* __restrict__ x,
                               const float* __restrict__ embed,
                               float* __restrict__ h) {
    int n = blockIdx.x;
    int d = threadIdx.x;                     // 0..127
    const float4* e = (const float4*)(embed + (size_t)x[n] * DMODEL);
    float4* hp = (float4*)(h + (size_t)n * DMODEL);
    hp[d] = e[d];
}

// ---------------------------------------------------------------------------
__global__ void bg_gather_k(const int* __restrict__ x,
                            const float* __restrict__ bge,
                            bf16_t* __restrict__ bgA) {
    int n = blockIdx.x;
    int t = n & (TSEQ - 1);
    int prev = (t == 0) ? 0 : x[n - 1];      // < 1024 < NB=2048
    bgA[(size_t)n * 128 + threadIdx.x] = (bf16_t)bge[(size_t)prev * 128 + threadIdx.x];
}

// ---------------------------------------------------------------------------
__global__ void cvt_bf16_k(const float* __restrict__ in, bf16_t* __restrict__ out, int n8) {
    int i = blockIdx.x * blockDim.x + threadIdx.x;
    if (i >= n8) return;
    float4 a = ((const float4*)in)[2 * i];
    float4 b = ((const float4*)in)[2 * i + 1];
    bf16x8 o;
    o[0] = (bf16_t)a.x; o[1] = (bf16_t)a.y; o[2] = (bf16_t)a.z; o[3] = (bf16_t)a.w;
    o[4] = (bf16_t)b.x; o[5] = (bf16_t)b.y; o[6] = (bf16_t)b.z; o[7] = (bf16_t)b.w;
    ((bf16x8*)out)[i] = o;
}

// ---------------------------------------------------------------------------
// RMSNorm f32 in -> bf16 out. One wave per row, 4 rows per block.
__global__ __launch_bounds__(256) void rmsnorm_k(const float* __restrict__ in,
                                                 const float* __restrict__ w,
                                                 bf16_t* __restrict__ out) {
    int wv = threadIdx.x >> 6, lane = threadIdx.x & 63;
    int row = (blockIdx.x << 2) + wv;
    const float* rp = in + (size_t)row * DMODEL + lane * 8;
    float4 v0 = *(const float4*)(rp);
    float4 v1 = *(const float4*)(rp + 4);
    float ss = v0.x*v0.x + v0.y*v0.y + v0.z*v0.z + v0.w*v0.w
             + v1.x*v1.x + v1.y*v1.y + v1.z*v1.z + v1.w*v1.w;
#pragma unroll
    for (int off = 32; off; off >>= 1) ss += __shfl_xor(ss, off, 64);
    float sc = rsqrtf(ss * (1.f / DMODEL) + 1e-6f);
    const float* wp = w + lane * 8;
    float4 w0 = *(const float4*)(wp);
    float4 w1 = *(const float4*)(wp + 4);
    bf16x8 o;
    o[0] = (bf16_t)(v0.x * sc * w0.x); o[1] = (bf16_t)(v0.y * sc * w0.y);
    o[2] = (bf16_t)(v0.z * sc * w0.z); o[3] = (bf16_t)(v0.w * sc * w0.w);
    o[4] = (bf16_t)(v1.x * sc * w1.x); o[5] = (bf16_t)(v1.y * sc * w1.y);
    o[6] = (bf16_t)(v1.z * sc * w1.z); o[7] = (bf16_t)(v1.w * sc * w1.w);
    *(bf16x8*)(out + (size_t)row * DMODEL + lane * 8) = o;
}

// ---------------------------------------------------------------------------
// bf16 MFMA GEMM: C[M,N] = A[M,K] @ B[N,K]^T
// BM in {128, 64}; BN = 128. 256 threads, 4 waves (2M x 2N), wave tile
// (BM/2) x 64, MI = BM/32 fragments in M.
// EPI: 0 = f32 store, 1 = f32 +=, 2 = bf16 relu(acc)^2,
//      4 = bf16 store with fused RoPE on cols < 1024 (QKV output)
template<int BM, int EPI>
__global__ __launch_bounds__(256) void gemm_mfma(const bf16_t* __restrict__ A,
                                                 const bf16_t* __restrict__ B,
                                                 float* __restrict__ Cf,
                                                 bf16_t* __restrict__ Cb,
                                                 const float* __restrict__ cosT,
                                                 const float* __restrict__ sinT,
                                                 int M, int N, int K) {
    constexpr int MI  = BM / 32;     // M fragments per wave (4 or 2)
    constexpr int ACH = BM / 64;     // A-staging 16B chunks per thread (2 or 1)
    __shared__ __align__(16) bf16_t As[BM * 32];
    __shared__ __align__(16) bf16_t Bs[128 * 32];
    const int tid = threadIdx.x;
    const int w = tid >> 6, lane = tid & 63;
    const int m0 = blockIdx.y * BM, n0 = blockIdx.x * 128;
    const int wr = (w >> 1) * (BM / 2), wc = (w & 1) * 64;
    const int fr = lane & 15, fq = lane >> 4;

    f32x4 acc[MI][4] = {};

    auto stage = [&](int k0) {
#pragma unroll
        for (int c = 0; c < ACH; ++c) {
            int idx = c * 256 + tid;
            int row = idx >> 2, cs = idx & 3;
            GLD16(A + (size_t)(m0 + row) * K + k0 + cs * 8,
                  As + (size_t)(c * 256 + w * 64) * 8);
        }
#pragma unroll
        for (int c = 0; c < 2; ++c) {
            int idx = c * 256 + tid;
            int row = idx >> 2, cs = idx & 3;
            GLD16(B + (size_t)(n0 + row) * K + k0 + cs * 8,
                  Bs + (size_t)(c * 256 + w * 64) * 8);
        }
    };

    stage(0);
    int k0 = 0;
    while (true) {
        asm volatile("s_waitcnt vmcnt(0)" ::: "memory");
        __syncthreads();
        bf16x8 a[MI], b[4];
        const bf16_t* ap = As + (size_t)(wr + fr) * 32 + fq * 8;
        const bf16_t* bp = Bs + (size_t)(wc + fr) * 32 + fq * 8;
#pragma unroll
        for (int i = 0; i < MI; ++i) a[i] = *(const bf16x8*)(ap + i * 16 * 32);
#pragma unroll
        for (int j = 0; j < 4; ++j)  b[j] = *(const bf16x8*)(bp + j * 16 * 32);
#pragma unroll
        for (int i = 0; i < MI; ++i)
#pragma unroll
            for (int j = 0; j < 4; ++j)
                acc[i][j] = __builtin_amdgcn_mfma_f32_16x16x32_bf16(a[i], b[j], acc[i][j], 0, 0, 0);
        k0 += 32;
        if (k0 >= K) break;
        __syncthreads();
        stage(k0);
    }

    // C/D layout: col = lane&15, row = (lane>>4)*4 + reg
    if (EPI == 4) {
        // wave's 64 cols = exactly one 64-wide head (n0, wc are 64-aligned)
        const bool qk = (n0 + wc) < 1024;   // q,k get RoPE; v plain
#pragma unroll
        for (int i = 0; i < MI; ++i) {
#pragma unroll
            for (int q = 0; q < 4; ++q) {
                int row = m0 + wr + i * 16 + fq * 4 + q;
                size_t rb = (size_t)row * N + n0 + wc;
                if (qk) {
                    int t = row & (TSEQ - 1);
#pragma unroll
                    for (int j = 0; j < 2; ++j) {
                        int d = j * 16 + fr;
                        float c = cosT[t * 32 + d];
                        float s = sinT[t * 32 + d];
                        float v1 = acc[i][j][q], v2 = acc[i][j + 2][q];
                        Cb[rb + j * 16 + fr]       = (bf16_t)(v1 * c - v2 * s);
                        Cb[rb + (j + 2) * 16 + fr] = (bf16_t)(v1 * s + v2 * c);
                    }
                } else {
#pragma unroll
                    for (int j = 0; j < 4; ++j)
                        Cb[rb + j * 16 + fr] = (bf16_t)acc[i][j][q];
                }
            }
        }
        return;
    }
#pragma unroll
    for (int i = 0; i < MI; ++i) {
        int row = m0 + wr + i * 16 + fq * 4;
#pragma unroll
        for (int j = 0; j < 4; ++j) {
            int col = n0 + wc + j * 16 + fr;
#pragma unroll
            for (int q = 0; q < 4; ++q) {
                float v = acc[i][j][q];
                size_t off = (size_t)(row + q) * N + col;
                if (EPI == 0)      Cf[off] = v;
                else if (EPI == 1) Cf[off] += v;
                else if (EPI == 2) { v = fmaxf(v, 0.f); Cb[off] = (bf16_t)(v * v); }
            }
        }
    }
}

// ---------------------------------------------------------------------------
// MFMA flash attention. Block = 4 waves; handles TWO q-blocks {p, 15-p} of
// one (b,h) sequentially -> uniform 17 tile-units per block (tail removed).
//   QK^T swapped:  S^T = K . Q^T  (16x16x32, K LDS chunk-XOR swizzle)
//   PV   swapped:  O^T = V^T . P^T (V^T via register 4x4 transpose, pad-72;
//                  P^T frags via uniform-index shfl + receiver select)
__global__ __launch_bounds__(256) void attn_mfma_k(const bf16_t* __restrict__ qkvb,
                                                   bf16_t* __restrict__ outb) {
    __shared__ __align__(16) bf16_t Ks[64 * 64];     // [key][slot^] chunk-XOR
    __shared__ __align__(16) bf16_t VsT[64 * 72];    // [d][key], rows padded to 72

    const int tid = threadIdx.x;
    const int w  = tid >> 6;
    const int ln = tid & 63;
    const int lr = ln & 15;       // q-lane
    const int lg = ln >> 4;       // lane group

    // XCD-chunked swizzle: 8 consecutive bh per XCD (KV set 2MB < 4MB L2)
    int raw = blockIdx.x;                  // 0..511
    int swz = (raw & 7) * 64 + (raw >> 3);
    const int bh = swz >> 3;
    const int b = bh >> 3, h = bh & 7;
    const int p = swz & 7;                 // pair index

    const bf16_t* Qg = qkvb + (size_t)b * TSEQ * 1536 + h * 64;
    const bf16_t* Kg = Qg + 512;
    const bf16_t* Vg = Qg + 1024;

    // V staging micro-tile assignment: keys mk*4..+3, d md*4..+3
    const int mk = tid >> 4;      // 0..15
    const int md = tid & 15;      // 0..15
    const int src0 = lr + 32 * (lg & 1);   // P source lanes: src0, src0+16
    const int fsel = lg >> 1;

    for (int pass = 0; pass < 2; ++pass) {
        const int qb   = pass ? (15 - p) : p;
        const int tq0b = qb << 6;
        const int tq0  = tq0b + w * 16;
        const int qrow = tq0 + lr;

        // Q regs (B-operand of swapped QK), prescaled by 0.125
        bf16x8 qreg[2];
        {
            const bf16_t* qp = Qg + (size_t)(tq0 + lr) * 1536 + lg * 8;
            qreg[0] = *(const bf16x8*)qp;
            qreg[1] = *(const bf16x8*)(qp + 32);
#pragma unroll
            for (int j = 0; j < 8; ++j) {
                qreg[0][j] = (bf16_t)((float)qreg[0][j] * 0.125f);
                qreg[1][j] = (bf16_t)((float)qreg[1][j] * 0.125f);
            }
        }

        f32x4 accO[4] = {};       // accO[dblk][r] = O[q=qrow][d=dblk*16+lg*4+r]
        float mrun = -1e30f, pl = 0.f, esf = 0.f;

        for (int t0 = 0; t0 <= tq0b; t0 += 64) {
            __syncthreads();      // prev-tile LDS reads done before overwrite

            // ---- K stage: GLD16, linear rows + chunk-XOR-swizzled source
#pragma unroll
            for (int ii = 0; ii < 2; ++ii) {
                const int i = w * 2 + ii;
                int key = i * 8 + (ln >> 3);
                int dc  = (ln & 7) ^ (ln >> 3);
                GLD16(Kg + (size_t)(t0 + key) * 1536 + dc * 8, Ks + i * 512);
            }
            // ---- V stage: b64 global reads, register 4x4 transpose, ds_write
            {
                bf16x4 rv[4];
#pragma unroll
                for (int i = 0; i < 4; ++i)
                    rv[i] = *(const bf16x4*)(Vg + (size_t)(t0 + mk * 4 + i) * 1536 + md * 4);
#pragma unroll
                for (int j = 0; j < 4; ++j) {
                    bf16x4 wv;
                    wv[0] = rv[0][j]; wv[1] = rv[1][j]; wv[2] = rv[2][j]; wv[3] = rv[3][j];
                    *(bf16x4*)(VsT + (size_t)(md * 4 + j) * 72 + mk * 4) = wv;
                }
            }
            __syncthreads();      // drains vmcnt (GLD16) + lgkmcnt (ds_write)

            // ---- QK^T (swapped): S^T[key][q]
            f32x4 sq[4] = {};
#pragma unroll
            for (int kr = 0; kr < 4; ++kr) {
                int key = kr * 16 + lr;
#pragma unroll
                for (int s = 0; s < 2; ++s) {
                    int chunk = key * 8 + ((s * 4 + lg) ^ (key & 7));
                    bf16x8 kf = *(const bf16x8*)(Ks + chunk * 8);
                    sq[kr] = __builtin_amdgcn_mfma_f32_16x16x32_bf16(kf, qreg[s], sq[kr], 0, 0, 0);
                }
            }

            // ---- online softmax; lane's q = qrow, 16 lane-local keys
            float pv[4][4];
            float tm = -1e30f;
#pragma unroll
            for (int f = 0; f < 4; ++f)
#pragma unroll
                for (int r = 0; r < 4; ++r) {
                    int key = t0 + f * 16 + lg * 4 + r;
                    float sv = (key <= qrow) ? sq[f][r] : -1e30f;
                    pv[f][r] = sv;
                    tm = fmaxf(tm, sv);
                }
            tm = fmaxf(tm, __shfl_xor(tm, 16, 64));
            tm = fmaxf(tm, __shfl_xor(tm, 32, 64));
            float mnew = fmaxf(mrun, tm);
            float corr = __expf(mrun - mnew);
            mrun = mnew;
            float psum = 0.f, pd = 0.f;
#pragma unroll
            for (int f = 0; f < 4; ++f)
#pragma unroll
                for (int r = 0; r < 4; ++r) {
                    float e = __expf(pv[f][r] - mnew);   // masked: exp(-huge)=0
                    pv[f][r] = e;
                    psum += e;
                    int key = t0 + f * 16 + lg * 4 + r;
                    pd = (key == qrow) ? e : pd;
                }
            pl  = pl  * corr + psum;
            esf = esf * corr + pd;
#pragma unroll
            for (int dblk = 0; dblk < 4; ++dblk)
#pragma unroll
                for (int r = 0; r < 4; ++r) accO[dblk][r] *= corr;

            // ---- pack P rows to bf16 pairs (uniform register indices only)
            u32 plo[4], phi[4];
#pragma unroll
            for (int f = 0; f < 4; ++f) {
                bf16x4 t;
                t[0] = (bf16_t)pv[f][0]; t[1] = (bf16_t)pv[f][1];
                t[2] = (bf16_t)pv[f][2]; t[3] = (bf16_t)pv[f][3];
                uint2 pr = __builtin_bit_cast(uint2, t);
                plo[f] = pr.x; phi[f] = pr.y;
            }

            // ---- PV (swapped): O^T = V^T . P^T
#pragma unroll
            for (int s = 0; s < 2; ++s) {
                u32 a0 = (u32)__shfl((int)plo[s * 2],     src0,      64);
                u32 a1 = (u32)__shfl((int)phi[s * 2],     src0,      64);
                u32 a2 = (u32)__shfl((int)plo[s * 2],     src0 + 16, 64);
                u32 a3 = (u32)__shfl((int)phi[s * 2],     src0 + 16, 64);
                u32 c0 = (u32)__shfl((int)plo[s * 2 + 1], src0,      64);
                u32 c1 = (u32)__shfl((int)phi[s * 2 + 1], src0,      64);
                u32 c2 = (u32)__shfl((int)plo[s * 2 + 1], src0 + 16, 64);
                u32 c3 = (u32)__shfl((int)phi[s * 2 + 1], src0 + 16, 64);
                u32x4 bw;
                bw[0] = fsel ? c0 : a0;
                bw[1] = fsel ? c1 : a1;
                bw[2] = fsel ? c2 : a2;
                bw[3] = fsel ? c3 : a3;
                bf16x8 bfrag = __builtin_bit_cast(bf16x8, bw);
#pragma unroll
                for (int dblk = 0; dblk < 4; ++dblk) {
                    bf16x8 av = *(const bf16x8*)(VsT + (size_t)(dblk * 16 + lr) * 72 + s * 32 + lg * 8);
                    accO[dblk] = __builtin_amdgcn_mfma_f32_16x16x32_bf16(av, bfrag, accO[dblk], 0, 0, 0);
                }
            }
        }

        // ---- epilogue: reduce l/self-weight over lane groups, subtract, store
        pl  += __shfl_xor(pl, 16, 64);  pl  += __shfl_xor(pl, 32, 64);
        esf += __shfl_xor(esf, 16, 64); esf += __shfl_xor(esf, 32, 64);
        float rin = 1.0f / pl;
        const bf16_t* vqp = Vg + (size_t)qrow * 1536;
        bf16_t* op = outb + (size_t)(b * TSEQ + qrow) * DMODEL + h * 64;
#pragma unroll
        for (int dblk = 0; dblk < 4; ++dblk) {
            bf16x4 vq = *(const bf16x4*)(vqp + dblk * 16 + lg * 4);
            bf16x4 o4;
#pragma unroll
            for (int r = 0; r < 4; ++r)
                o4[r] = (bf16_t)((accO[dblk][r] - esf * (float)vq[r]) * rin);
            *(bf16x4*)(op + dblk * 16 + lg * 4) = o4;
        }
    }
}

// ---------------------------------------------------------------------------
static inline void cvt(const float* in, bf16_t* out, size_t n, hipStream_t s) {
    int n8 = (int)(n / 8);
    cvt_bf16_k<<<(n8 + 255) / 256, 256, 0, s>>>(in, out, n8);
}

extern "C" void kernel_launch(void* const* d_in, const int* in_sizes, int n_in,
                              void* d_out, int out_size, void* d_ws, size_t ws_size,
                              hipStream_t stream) {
    const int*   x     = (const int*)d_in[0];
    const float* embed = (const float*)d_in[1];
    const float* Wqkv  = (const float*)d_in[2];
    const float* Wproj = (const float*)d_in[3];
    const float* n1w   = (const float*)d_in[4];
    const float* n2w   = (const float*)d_in[5];
    const float* Wfc1  = (const float*)d_in[6];
    const float* Wfc2  = (const float*)d_in[7];
    const float* normf = (const float*)d_in[8];
    const float* bge   = (const float*)d_in[9];
    const float* bgp   = (const float*)d_in[10];
    float* out = (float*)d_out;

    // workspace layout (~118 MB)
    float* ws   = (float*)d_ws;
    float* cosT = ws;                            // 32768
    float* sinT = cosT + 32768;                  // 32768
    float* h    = sinT + 32768;                  // 8192*512 f32
    bf16_t* qkvb = (bf16_t*)(h + (size_t)NROW * DMODEL);  // 8192*1536 bf16
    bf16_t* ub   = qkvb;                         // alias: qkvb dead when fc1 runs
    bf16_t* xn   = qkvb + (size_t)NROW * 1536;
    bf16_t* atb  = xn  + (size_t)NROW * DMODEL;
    bf16_t* bga  = atb + (size_t)NROW * DMODEL;  // 8192*128
    bf16_t* wqb  = bga + (size_t)NROW * 128;
    bf16_t* wpb  = wqb + (size_t)LAYERS * 3 * DMODEL * DMODEL;
    bf16_t* w1b  = wpb + (size_t)LAYERS * DMODEL * DMODEL;
    bf16_t* w2b  = w1b + (size_t)LAYERS * HIDDEN * DMODEL;
    bf16_t* embb = w2b + (size_t)LAYERS * DMODEL * HIDDEN;
    bf16_t* bgpb = embb + (size_t)1024 * DMODEL;

    rope_table_k<<<128, 256, 0, stream>>>(cosT, sinT);
    embed_gather_k<<<NROW, 128, 0, stream>>>(x, embed, h);
    bg_gather_k<<<NROW, 128, 0, stream>>>(x, bge, bga);

    cvt(Wqkv,  wqb,  (size_t)LAYERS * 3 * DMODEL * DMODEL, stream);
    cvt(Wproj, wpb,  (size_t)LAYERS * DMODEL * DMODEL, stream);
    cvt(Wfc1,  w1b,  (size_t)LAYERS * HIDDEN * DMODEL, stream);
    cvt(Wfc2,  w2b,  (size_t)LAYERS * DMODEL * HIDDEN, stream);
    cvt(embed, embb, (size_t)1024 * DMODEL, stream);
    cvt(bgp,   bgpb, (size_t)1024 * 128, stream);

    for (int i = 0; i < LAYERS; ++i) {
        rmsnorm_k<<<NROW / 4, 256, 0, stream>>>(h, n1w + i * DMODEL, xn);
        gemm_mfma<128, 4><<<dim3(12, 64), 256, 0, stream>>>(
            xn, wqb + (size_t)i * 3 * DMODEL * DMODEL, nullptr, qkvb,
            cosT, sinT, NROW, 3 * DMODEL, DMODEL);
        attn_mfma_k<<<512, 256, 0, stream>>>(qkvb, atb);
        gemm_mfma<64, 1><<<dim3(4, 128), 256, 0, stream>>>(
            atb, wpb + (size_t)i * DMODEL * DMODEL, h, nullptr,
            nullptr, nullptr, NROW, DMODEL, DMODEL);
        rmsnorm_k<<<NROW / 4, 256, 0, stream>>>(h, n2w + i * DMODEL, xn);
        gemm_mfma<128, 2><<<dim3(12, 64), 256, 0, stream>>>(
            xn, w1b + (size_t)i * HIDDEN * DMODEL, nullptr, ub,
            nullptr, nullptr, NROW, HIDDEN, DMODEL);
        gemm_mfma<64, 1><<<dim3(4, 128), 256, 0, stream>>>(
            ub, w2b + (size_t)i * DMODEL * HIDDEN, h, nullptr,
            nullptr, nullptr, NROW, DMODEL, HIDDEN);
    }

    rmsnorm_k<<<NROW / 4, 256, 0, stream>>>(h, normf, xn);
    gemm_mfma<64, 0><<<dim3(8, 128), 256, 0, stream>>>(
        xn, embb, out, nullptr, nullptr, nullptr, NROW, 1024, DMODEL);
    gemm_mfma<64, 1><<<dim3(8, 128), 256, 0, stream>>>(
        bga, bgpb, out, nullptr, nullptr, nullptr, NROW, 1024, 128);
}

// Round 6
// 1667.727 us; speedup vs baseline: 7.8334x; 1.1767x over previous
//
#include <hip/hip_runtime.h>

// Problem constants
#define NROW   8192     // B*T
#define DMODEL 512
#define TSEQ   1024
#define LAYERS 11
#define HIDDEN 1536

typedef __bf16 bf16_t;
typedef bf16_t bf16x8 __attribute__((ext_vector_type(8)));
typedef bf16_t bf16x4 __attribute__((ext_vector_type(4)));
typedef float  f32x4  __attribute__((ext_vector_type(4)));
typedef unsigned int u32;
typedef u32 u32x4 __attribute__((ext_vector_type(4)));

#define GLD16(gp, lp) __builtin_amdgcn_global_load_lds( \
    (const __attribute__((address_space(1))) void*)(gp), \
    (__attribute__((address_space(3))) void*)(lp), 16, 0, 0)

// ---------------------------------------------------------------------------
__global__ void rope_table_k(float* __restrict__ cosT, float* __restrict__ sinT) {
    int i = blockIdx.x * blockDim.x + threadIdx.x;   // 0..32767
    int t = i >> 5, j = i & 31;
    float freq = powf(10000.f, -(float)j * (1.f / 32.f));
    float ang = (float)t * freq;
    cosT[i] = cosf(ang);
    sinT[i] = sinf(ang);
}

// ---------------------------------------------------------------------------
__global__ void embed_gather_k(const int* __restrict__ x,
                               const float* __restrict__ embed,
                               float* __restrict__ h) {
    int n = blockIdx.x;
    int d = threadIdx.x;                     // 0..127
    const float4* e = (const float4*)(embed + (size_t)x[n] * DMODEL);
    float4* hp = (float4*)(h + (size_t)n * DMODEL);
    hp[d] = e[d];
}

// ---------------------------------------------------------------------------
__global__ void bg_gather_k(const int* __restrict__ x,
                            const float* __restrict__ bge,
                            bf16_t* __restrict__ bgA) {
    int n = blockIdx.x;
    int t = n & (TSEQ - 1);
    int prev = (t == 0) ? 0 : x[n - 1];      // < 1024 < NB=2048
    bgA[(size_t)n * 128 + threadIdx.x] = (bf16_t)bge[(size_t)prev * 128 + threadIdx.x];
}

// ---------------------------------------------------------------------------
__global__ void cvt_bf16_k(const float* __restrict__ in, bf16_t* __restrict__ out, int n8) {
    int i = blockIdx.x * blockDim.x + threadIdx.x;
    if (i >= n8) return;
    float4 a = ((const float4*)in)[2 * i];
    float4 b = ((const float4*)in)[2 * i + 1];
    bf16x8 o;
    o[0] = (bf16_t)a.x; o[1] = (bf16_t)a.y; o[2] = (bf16_t)a.z; o[3] = (bf16_t)a.w;
    o[4] = (bf16_t)b.x; o[5] = (bf16_t)b.y; o[6] = (bf16_t)b.z; o[7] = (bf16_t)b.w;
    ((bf16x8*)out)[i] = o;
}

// ---------------------------------------------------------------------------
// RMSNorm f32 in -> bf16 out. One wave per row, 4 rows per block.
__global__ __launch_bounds__(256) void rmsnorm_k(const float* __restrict__ in,
                                                 const float* __restrict__ w,
                                                 bf16_t* __restrict__ out) {
    int wv = threadIdx.x >> 6, lane = threadIdx.x & 63;
    int row = (blockIdx.x << 2) + wv;
    const float* rp = in + (size_t)row * DMODEL + lane * 8;
    float4 v0 = *(const float4*)(rp);
    float4 v1 = *(const float4*)(rp + 4);
    float ss = v0.x*v0.x + v0.y*v0.y + v0.z*v0.z + v0.w*v0.w
             + v1.x*v1.x + v1.y*v1.y + v1.z*v1.z + v1.w*v1.w;
#pragma unroll
    for (int off = 32; off; off >>= 1) ss += __shfl_xor(ss, off, 64);
    float sc = rsqrtf(ss * (1.f / DMODEL) + 1e-6f);
    const float* wp = w + lane * 8;
    float4 w0 = *(const float4*)(wp);
    float4 w1 = *(const float4*)(wp + 4);
    bf16x8 o;
    o[0] = (bf16_t)(v0.x * sc * w0.x); o[1] = (bf16_t)(v0.y * sc * w0.y);
    o[2] = (bf16_t)(v0.z * sc * w0.z); o[3] = (bf16_t)(v0.w * sc * w0.w);
    o[4] = (bf16_t)(v1.x * sc * w1.x); o[5] = (bf16_t)(v1.y * sc * w1.y);
    o[6] = (bf16_t)(v1.z * sc * w1.z); o[7] = (bf16_t)(v1.w * sc * w1.w);
    *(bf16x8*)(out + (size_t)row * DMODEL + lane * 8) = o;
}

// ---------------------------------------------------------------------------
// bf16 MFMA GEMM: C[M,N] = A[M,K] @ B[N,K]^T
// Double-buffered LDS, counted vmcnt, raw s_barrier (no full drain per step).
// 1D grid with bijective XCD-chunked swizzle (grid % 8 == 0 always here).
// BM in {128, 64}; BN = 128. 256 threads, 4 waves (2M x 2N).
// EPI: 0 = f32 store, 1 = f32 +=, 2 = bf16 relu(acc)^2,
//      4 = bf16 store with fused RoPE on cols < 1024 (QKV output)
template<int BM, int EPI>
__global__ __launch_bounds__(256) void gemm_mfma(const bf16_t* __restrict__ A,
                                                 const bf16_t* __restrict__ B,
                                                 float* __restrict__ Cf,
                                                 bf16_t* __restrict__ Cb,
                                                 const float* __restrict__ cosT,
                                                 const float* __restrict__ sinT,
                                                 int M, int N, int K, int nbx) {
    constexpr int MI  = BM / 32;     // M fragments per wave (4 or 2)
    constexpr int ACH = BM / 64;     // A-staging 16B chunks per thread (2 or 1)
    __shared__ __align__(16) bf16_t As[2][BM * 32];
    __shared__ __align__(16) bf16_t Bs[2][128 * 32];
    const int tid = threadIdx.x;
    const int w = tid >> 6, lane = tid & 63;

    // bijective XCD-chunk swizzle: XCD x gets a contiguous by-range
    const int nwg = (int)gridDim.x;
    const int bid = blockIdx.x;
    const int swz = (bid & 7) * (nwg >> 3) + (bid >> 3);
    const int bx = swz % nbx, by = swz / nbx;

    const int m0 = by * BM, n0 = bx * 128;
    const int wr = (w >> 1) * (BM / 2), wc = (w & 1) * 64;
    const int fr = lane & 15, fq = lane >> 4;

    f32x4 acc[MI][4] = {};

    auto stage = [&](int k0, int buf) {
#pragma unroll
        for (int c = 0; c < ACH; ++c) {
            int idx = c * 256 + tid;
            int row = idx >> 2, cs = idx & 3;
            GLD16(A + (size_t)(m0 + row) * K + k0 + cs * 8,
                  &As[buf][(size_t)(c * 256 + w * 64) * 8]);
        }
#pragma unroll
        for (int c = 0; c < 2; ++c) {
            int idx = c * 256 + tid;
            int row = idx >> 2, cs = idx & 3;
            GLD16(B + (size_t)(n0 + row) * K + k0 + cs * 8,
                  &Bs[buf][(size_t)(c * 256 + w * 64) * 8]);
        }
    };

    const int NK = K >> 5;
    stage(0, 0);
    for (int k = 0; k < NK; ++k) {
        const int cur = k & 1;
        if (k + 1 < NK) {
            stage((k + 1) << 5, cur ^ 1);
            // wait only for stage(k): the LPT newest (stage k+1) may remain in flight
            if constexpr (BM == 128) asm volatile("s_waitcnt vmcnt(4)" ::: "memory");
            else                     asm volatile("s_waitcnt vmcnt(3)" ::: "memory");
        } else {
            asm volatile("s_waitcnt vmcnt(0)" ::: "memory");
        }
        __builtin_amdgcn_s_barrier();
        __builtin_amdgcn_sched_barrier(0);

        bf16x8 a[MI], b[4];
        const bf16_t* ap = &As[cur][(size_t)(wr + fr) * 32 + fq * 8];
        const bf16_t* bp = &Bs[cur][(size_t)(wc + fr) * 32 + fq * 8];
#pragma unroll
        for (int i = 0; i < MI; ++i) a[i] = *(const bf16x8*)(ap + i * 16 * 32);
#pragma unroll
        for (int j = 0; j < 4; ++j)  b[j] = *(const bf16x8*)(bp + j * 16 * 32);
#pragma unroll
        for (int i = 0; i < MI; ++i)
#pragma unroll
            for (int j = 0; j < 4; ++j)
                acc[i][j] = __builtin_amdgcn_mfma_f32_16x16x32_bf16(a[i], b[j], acc[i][j], 0, 0, 0);

        asm volatile("s_waitcnt lgkmcnt(0)" ::: "memory");
        __builtin_amdgcn_s_barrier();        // all waves done reading buf cur
        __builtin_amdgcn_sched_barrier(0);
    }

    // C/D layout: col = lane&15, row = (lane>>4)*4 + reg
    if (EPI == 4) {
        // wave's 64 cols = exactly one 64-wide head (n0, wc are 64-aligned)
        const bool qk = (n0 + wc) < 1024;   // q,k get RoPE; v plain
#pragma unroll
        for (int i = 0; i < MI; ++i) {
#pragma unroll
            for (int q = 0; q < 4; ++q) {
                int row = m0 + wr + i * 16 + fq * 4 + q;
                size_t rb = (size_t)row * N + n0 + wc;
                if (qk) {
                    int t = row & (TSEQ - 1);
#pragma unroll
                    for (int j = 0; j < 2; ++j) {
                        int d = j * 16 + fr;
                        float c = cosT[t * 32 + d];
                        float s = sinT[t * 32 + d];
                        float v1 = acc[i][j][q], v2 = acc[i][j + 2][q];
                        Cb[rb + j * 16 + fr]       = (bf16_t)(v1 * c - v2 * s);
                        Cb[rb + (j + 2) * 16 + fr] = (bf16_t)(v1 * s + v2 * c);
                    }
                } else {
#pragma unroll
                    for (int j = 0; j < 4; ++j)
                        Cb[rb + j * 16 + fr] = (bf16_t)acc[i][j][q];
                }
            }
        }
        return;
    }
#pragma unroll
    for (int i = 0; i < MI; ++i) {
        int row = m0 + wr + i * 16 + fq * 4;
#pragma unroll
        for (int j = 0; j < 4; ++j) {
            int col = n0 + wc + j * 16 + fr;
#pragma unroll
            for (int q = 0; q < 4; ++q) {
                float v = acc[i][j][q];
                size_t off = (size_t)(row + q) * N + col;
                if (EPI == 0)      Cf[off] = v;
                else if (EPI == 1) Cf[off] += v;
                else if (EPI == 2) { v = fmaxf(v, 0.f); Cb[off] = (bf16_t)(v * v); }
            }
        }
    }
}

// ---------------------------------------------------------------------------
// MFMA flash attention. Block = 4 waves; handles TWO q-blocks {p, 15-p} of
// one (b,h) sequentially -> uniform 17 tile-units per block.
// K/V double-buffered in LDS; next tile's K (GLD16) and V (global->reg) are
// issued BEFORE this tile's compute, drained with one vmcnt(0) after PV and
// one barrier per tile.
//   QK^T swapped:  S^T = K . Q^T  (16x16x32, K LDS chunk-XOR swizzle)
//   PV   swapped:  O^T = V^T . P^T (V^T rows 128B + byte^((row&7)<<4) XOR;
//                  P^T frags via uniform-index shfl + receiver select)
__global__ __launch_bounds__(256) void attn_mfma_k(const bf16_t* __restrict__ qkvb,
                                                   bf16_t* __restrict__ outb) {
    __shared__ __align__(16) bf16_t Ks[2][64 * 64];    // [key][slot^] chunk-XOR
    __shared__ __align__(16) bf16_t VsT[2][64 * 64];   // [d][key^] granule-XOR

    const int tid = threadIdx.x;
    const int w  = tid >> 6;
    const int ln = tid & 63;
    const int lr = ln & 15;       // q-lane
    const int lg = ln >> 4;       // lane group

    // XCD-chunked swizzle: 8 consecutive bh per XCD
    int raw = blockIdx.x;                  // 0..511
    int swz = (raw & 7) * 64 + (raw >> 3);
    const int bh = swz >> 3;
    const int b = bh >> 3, h = bh & 7;
    const int p = swz & 7;                 // pair index

    const bf16_t* Qg = qkvb + (size_t)b * TSEQ * 1536 + h * 64;
    const bf16_t* Kg = Qg + 512;
    const bf16_t* Vg = Qg + 1024;

    // V staging micro-tile: keys mk*4..+3, d md*4..+3
    const int mk = tid >> 4;      // 0..15
    const int md = tid & 15;      // 0..15
    const int src0 = lr + 32 * (lg & 1);   // P source lanes: src0, src0+16
    const int fsel = lg >> 1;

    // K stage: linear rows, chunk-XOR-swizzled global source
    const int ks_key = w * 16 + (ln >> 3) * 2;        // rows staged by this wave
    auto KSTAGE = [&](int t0, int buf) {
#pragma unroll
        for (int ii = 0; ii < 2; ++ii) {
            const int i = w * 2 + ii;
            int key = i * 8 + (ln >> 3);
            int dc  = (ln & 7) ^ (ln >> 3);
            GLD16(Kg + (size_t)(t0 + key) * 1536 + dc * 8, &Ks[buf][i * 512]);
        }
    };
    auto VLOAD = [&](int t0, bf16x4* rv) {
#pragma unroll
        for (int i = 0; i < 4; ++i)
            rv[i] = *(const bf16x4*)(Vg + (size_t)(t0 + mk * 4 + i) * 1536 + md * 4);
    };
    auto VWRITE = [&](const bf16x4* rv, int buf) {
#pragma unroll
        for (int j = 0; j < 4; ++j) {
            int row = md * 4 + j;
            bf16x4 wv;
            wv[0] = rv[0][j]; wv[1] = rv[1][j]; wv[2] = rv[2][j]; wv[3] = rv[3][j];
            int pe = row * 64 + (((mk >> 1) ^ (row & 7)) << 3) + (mk & 1) * 4;
            *(bf16x4*)&VsT[buf][pe] = wv;
        }
    };

    for (int pass = 0; pass < 2; ++pass) {
        const int qb   = pass ? (15 - p) : p;
        const int tq0b = qb << 6;
        const int tq0  = tq0b + w * 16;
        const int qrow = tq0 + lr;

        // Q regs (B-operand of swapped QK), prescaled by 0.125
        bf16x8 qreg[2];
        {
            const bf16_t* qp = Qg + (size_t)qrow * 1536 + lg * 8;
            qreg[0] = *(const bf16x8*)qp;
            qreg[1] = *(const bf16x8*)(qp + 32);
#pragma unroll
            for (int j = 0; j < 8; ++j) {
                qreg[0][j] = (bf16_t)((float)qreg[0][j] * 0.125f);
                qreg[1][j] = (bf16_t)((float)qreg[1][j] * 0.125f);
            }
        }

        f32x4 accO[4] = {};       // accO[dblk][r] = O[q=qrow][d=dblk*16+lg*4+r]
        float mrun = -1e30f, pl = 0.f, esf = 0.f;

        // prologue: stage tile 0 into buf 0
        {
            bf16x4 rv[4];
            KSTAGE(0, 0);
            VLOAD(0, rv);
            asm volatile("s_waitcnt vmcnt(0)" ::: "memory");
            VWRITE(rv, 0);
            asm volatile("s_waitcnt lgkmcnt(0)" ::: "memory");
            __builtin_amdgcn_s_barrier();
            __builtin_amdgcn_sched_barrier(0);
        }

        for (int t0 = 0; t0 <= tq0b; t0 += 64) {
            const int cur = (t0 >> 6) & 1;
            const bool more = t0 < tq0b;
            bf16x4 rv[4];
            if (more) {                     // issue next tile's loads early
                KSTAGE(t0 + 64, cur ^ 1);
                VLOAD(t0 + 64, rv);
            }

            // ---- QK^T (swapped): S^T[key][q]
            f32x4 sq[4] = {};
#pragma unroll
            for (int kr = 0; kr < 4; ++kr) {
                int key = kr * 16 + lr;
#pragma unroll
                for (int s = 0; s < 2; ++s) {
                    int chunk = key * 8 + ((s * 4 + lg) ^ (key & 7));
                    bf16x8 kf = *(const bf16x8*)&Ks[cur][chunk * 8];
                    sq[kr] = __builtin_amdgcn_mfma_f32_16x16x32_bf16(kf, qreg[s], sq[kr], 0, 0, 0);
                }
            }

            // ---- online softmax; lane's q = qrow, 16 lane-local keys
            float pv[4][4];
            float tm = -1e30f;
#pragma unroll
            for (int f = 0; f < 4; ++f)
#pragma unroll
                for (int r = 0; r < 4; ++r) {
                    int key = t0 + f * 16 + lg * 4 + r;
                    float sv = (key <= qrow) ? sq[f][r] : -1e30f;
                    pv[f][r] = sv;
                    tm = fmaxf(tm, sv);
                }
            tm = fmaxf(tm, __shfl_xor(tm, 16, 64));
            tm = fmaxf(tm, __shfl_xor(tm, 32, 64));
            float mnew = fmaxf(mrun, tm);
            float corr = __expf(mrun - mnew);
            mrun = mnew;
            float psum = 0.f, pd = 0.f;
#pragma unroll
            for (int f = 0; f < 4; ++f)
#pragma unroll
                for (int r = 0; r < 4; ++r) {
                    float e = __expf(pv[f][r] - mnew);   // masked: exp(-huge)=0
                    pv[f][r] = e;
                    psum += e;
                    int key = t0 + f * 16 + lg * 4 + r;
                    pd = (key == qrow) ? e : pd;
                }
            pl  = pl  * corr + psum;
            esf = esf * corr + pd;
#pragma unroll
            for (int dblk = 0; dblk < 4; ++dblk)
#pragma unroll
                for (int r = 0; r < 4; ++r) accO[dblk][r] *= corr;

            // ---- pack P rows to bf16 pairs (uniform register indices only)
            u32 plo[4], phi[4];
#pragma unroll
            for (int f = 0; f < 4; ++f) {
                bf16x4 t;
                t[0] = (bf16_t)pv[f][0]; t[1] = (bf16_t)pv[f][1];
                t[2] = (bf16_t)pv[f][2]; t[3] = (bf16_t)pv[f][3];
                uint2 pr = __builtin_bit_cast(uint2, t);
                plo[f] = pr.x; phi[f] = pr.y;
            }

            // ---- PV (swapped): O^T = V^T . P^T
#pragma unroll
            for (int s = 0; s < 2; ++s) {
                u32 a0 = (u32)__shfl((int)plo[s * 2],     src0,      64);
                u32 a1 = (u32)__shfl((int)phi[s * 2],     src0,      64);
                u32 a2 = (u32)__shfl((int)plo[s * 2],     src0 + 16, 64);
                u32 a3 = (u32)__shfl((int)phi[s * 2],     src0 + 16, 64);
                u32 c0 = (u32)__shfl((int)plo[s * 2 + 1], src0,      64);
                u32 c1 = (u32)__shfl((int)phi[s * 2 + 1], src0,      64);
                u32 c2 = (u32)__shfl((int)plo[s * 2 + 1], src0 + 16, 64);
                u32 c3 = (u32)__shfl((int)phi[s * 2 + 1], src0 + 16, 64);
                u32x4 bw;
                bw[0] = fsel ? c0 : a0;
                bw[1] = fsel ? c1 : a1;
                bw[2] = fsel ? c2 : a2;
                bw[3] = fsel ? c3 : a3;
                bf16x8 bfrag = __builtin_bit_cast(bf16x8, bw);
#pragma unroll
                for (int dblk = 0; dblk < 4; ++dblk) {
                    int row = dblk * 16 + lr;
                    int pe = row * 64 + (((s * 4 + lg) ^ (row & 7)) << 3);
                    bf16x8 av = *(const bf16x8*)&VsT[cur][pe];
                    accO[dblk] = __builtin_amdgcn_mfma_f32_16x16x32_bf16(av, bfrag, accO[dblk], 0, 0, 0);
                }
            }

            // ---- land next tile's V into the other buffer; close the tile
            if (more) {
                asm volatile("s_waitcnt vmcnt(0)" ::: "memory");
                VWRITE(rv, cur ^ 1);
            }
            asm volatile("s_waitcnt lgkmcnt(0)" ::: "memory");
            __builtin_amdgcn_s_barrier();
            __builtin_amdgcn_sched_barrier(0);
        }

        // ---- epilogue: reduce l/self-weight over lane groups, subtract, store
        pl  += __shfl_xor(pl, 16, 64);  pl  += __shfl_xor(pl, 32, 64);
        esf += __shfl_xor(esf, 16, 64); esf += __shfl_xor(esf, 32, 64);
        float rin = 1.0f / pl;
        const bf16_t* vqp = Vg + (size_t)qrow * 1536;
        bf16_t* op = outb + (size_t)(b * TSEQ + qrow) * DMODEL + h * 64;
#pragma unroll
        for (int dblk = 0; dblk < 4; ++dblk) {
            bf16x4 vq = *(const bf16x4*)(vqp + dblk * 16 + lg * 4);
            bf16x4 o4;
#pragma unroll
            for (int r = 0; r < 4; ++r)
                o4[r] = (bf16_t)((accO[dblk][r] - esf * (float)vq[r]) * rin);
            *(bf16x4*)(op + dblk * 16 + lg * 4) = o4;
        }
    }
}

// ---------------------------------------------------------------------------
static inline void cvt(const float* in, bf16_t* out, size_t n, hipStream_t s) {
    int n8 = (int)(n / 8);
    cvt_bf16_k<<<(n8 + 255) / 256, 256, 0, s>>>(in, out, n8);
}

extern "C" void kernel_launch(void* const* d_in, const int* in_sizes, int n_in,
                              void* d_out, int out_size, void* d_ws, size_t ws_size,
                              hipStream_t stream) {
    const int*   x     = (const int*)d_in[0];
    const float* embed = (const float*)d_in[1];
    const float* Wqkv  = (const float*)d_in[2];
    const float* Wproj = (const float*)d_in[3];
    const float* n1w   = (const float*)d_in[4];
    const float* n2w   = (const float*)d_in[5];
    const float* Wfc1  = (const float*)d_in[6];
    const float* Wfc2  = (const float*)d_in[7];
    const float* normf = (const float*)d_in[8];
    const float* bge   = (const float*)d_in[9];
    const float* bgp   = (const float*)d_in[10];
    float* out = (float*)d_out;

    // workspace layout (~118 MB)
    float* ws   = (float*)d_ws;
    float* cosT = ws;                            // 32768
    float* sinT = cosT + 32768;                  // 32768
    float* h    = sinT + 32768;                  // 8192*512 f32
    bf16_t* qkvb = (bf16_t*)(h + (size_t)NROW * DMODEL);  // 8192*1536 bf16
    bf16_t* ub   = qkvb;                         // alias: qkvb dead when fc1 runs
    bf16_t* xn   = qkvb + (size_t)NROW * 1536;
    bf16_t* atb  = xn  + (size_t)NROW * DMODEL;
    bf16_t* bga  = atb + (size_t)NROW * DMODEL;  // 8192*128
    bf16_t* wqb  = bga + (size_t)NROW * 128;
    bf16_t* wpb  = wqb + (size_t)LAYERS * 3 * DMODEL * DMODEL;
    bf16_t* w1b  = wpb + (size_t)LAYERS * DMODEL * DMODEL;
    bf16_t* w2b  = w1b + (size_t)LAYERS * HIDDEN * DMODEL;
    bf16_t* embb = w2b + (size_t)LAYERS * DMODEL * HIDDEN;
    bf16_t* bgpb = embb + (size_t)1024 * DMODEL;

    rope_table_k<<<128, 256, 0, stream>>>(cosT, sinT);
    embed_gather_k<<<NROW, 128, 0, stream>>>(x, embed, h);
    bg_gather_k<<<NROW, 128, 0, stream>>>(x, bge, bga);

    cvt(Wqkv,  wqb,  (size_t)LAYERS * 3 * DMODEL * DMODEL, stream);
    cvt(Wproj, wpb,  (size_t)LAYERS * DMODEL * DMODEL, stream);
    cvt(Wfc1,  w1b,  (size_t)LAYERS * HIDDEN * DMODEL, stream);
    cvt(Wfc2,  w2b,  (size_t)LAYERS * DMODEL * HIDDEN, stream);
    cvt(embed, embb, (size_t)1024 * DMODEL, stream);
    cvt(bgp,   bgpb, (size_t)1024 * 128, stream);

    for (int i = 0; i < LAYERS; ++i) {
        rmsnorm_k<<<NROW / 4, 256, 0, stream>>>(h, n1w + i * DMODEL, xn);
        gemm_mfma<128, 4><<<768, 256, 0, stream>>>(
            xn, wqb + (size_t)i * 3 * DMODEL * DMODEL, nullptr, qkvb,
            cosT, sinT, NROW, 3 * DMODEL, DMODEL, 12);
        attn_mfma_k<<<512, 256, 0, stream>>>(qkvb, atb);
        gemm_mfma<64, 1><<<512, 256, 0, stream>>>(
            atb, wpb + (size_t)i * DMODEL * DMODEL, h, nullptr,
            nullptr, nullptr, NROW, DMODEL, DMODEL, 4);
        rmsnorm_k<<<NROW / 4, 256, 0, stream>>>(h, n2w + i * DMODEL, xn);
        gemm_mfma<128, 2><<<768, 256, 0, stream>>>(
            xn, w1b + (size_t)i * HIDDEN * DMODEL, nullptr, ub,
            nullptr, nullptr, NROW, HIDDEN, DMODEL, 12);
        gemm_mfma<64, 1><<<512, 256, 0, stream>>>(
            ub, w2b + (size_t)i * DMODEL * HIDDEN, h, nullptr,
            nullptr, nullptr, NROW, DMODEL, HIDDEN, 4);
    }

    rmsnorm_k<<<NROW / 4, 256, 0, stream>>>(h, normf, xn);
    gemm_mfma<64, 0><<<1024, 256, 0, stream>>>(
        xn, embb, out, nullptr, nullptr, nullptr, NROW, 1024, DMODEL, 8);
    gemm_mfma<64, 1><<<1024, 256, 0, stream>>>(
        bga, bgpb, out, nullptr, nullptr, nullptr, NROW, 1024, 128, 8);
}

// Round 7
// 1592.265 us; speedup vs baseline: 8.2047x; 1.0474x over previous
//
#include <hip/hip_runtime.h>

// Problem constants
#define NROW   8192     // B*T
#define DMODEL 512
#define TSEQ   1024
#define LAYERS 11
#define HIDDEN 1536

typedef __bf16 bf16_t;
typedef bf16_t bf16x8 __attribute__((ext_vector_type(8)));
typedef bf16_t bf16x4 __attribute__((ext_vector_type(4)));
typedef float  f32x4  __attribute__((ext_vector_type(4)));
typedef unsigned int u32;
typedef u32 u32x4 __attribute__((ext_vector_type(4)));

#define GLD16(gp, lp) __builtin_amdgcn_global_load_lds( \
    (const __attribute__((address_space(1))) void*)(gp), \
    (__attribute__((address_space(3))) void*)(lp), 16, 0, 0)

// ---------------------------------------------------------------------------
__global__ void rope_table_k(float* __restrict__ cosT, float* __restrict__ sinT) {
    int i = blockIdx.x * blockDim.x + threadIdx.x;   // 0..32767
    int t = i >> 5, j = i & 31;
    float freq = powf(10000.f, -(float)j * (1.f / 32.f));
    float ang = (float)t * freq;
    cosT[i] = cosf(ang);
    sinT[i] = sinf(ang);
}

// ---------------------------------------------------------------------------
__global__ void embed_gather_k(const int* __restrict__ x,
                               const float* __restrict__ embed,
                               float* __restrict__ h) {
    int n = blockIdx.x;
    int d = threadIdx.x;                     // 0..127
    const float4* e = (const float4*)(embed + (size_t)x[n] * DMODEL);
    float4* hp = (float4*)(h + (size_t)n * DMODEL);
    hp[d] = e[d];
}

// ---------------------------------------------------------------------------
// writes bigram A-slice into fused-A cols 512..639 (row stride 640)
__global__ void bg_gather_k(const int* __restrict__ x,
                            const float* __restrict__ bge,
                            bf16_t* __restrict__ Afu) {
    int n = blockIdx.x;
    int t = n & (TSEQ - 1);
    int prev = (t == 0) ? 0 : x[n - 1];      // < 1024 < NB=2048
    Afu[(size_t)n * 640 + 512 + threadIdx.x] = (bf16_t)bge[(size_t)prev * 128 + threadIdx.x];
}

// ---------------------------------------------------------------------------
__global__ void cvt_bf16_k(const float* __restrict__ in, bf16_t* __restrict__ out, int n8) {
    int i = blockIdx.x * blockDim.x + threadIdx.x;
    if (i >= n8) return;
    float4 a = ((const float4*)in)[2 * i];
    float4 b = ((const float4*)in)[2 * i + 1];
    bf16x8 o;
    o[0] = (bf16_t)a.x; o[1] = (bf16_t)a.y; o[2] = (bf16_t)a.z; o[3] = (bf16_t)a.w;
    o[4] = (bf16_t)b.x; o[5] = (bf16_t)b.y; o[6] = (bf16_t)b.z; o[7] = (bf16_t)b.w;
    ((bf16x8*)out)[i] = o;
}

// ---------------------------------------------------------------------------
// f32 [rows][cols] -> bf16 into [rows][640] at colOff  (cols = 1<<lshift)
__global__ void cvt_pad_k(const float* __restrict__ in, bf16_t* __restrict__ out,
                          int n8, int lshift, int mask, int colOff) {
    int i = blockIdx.x * blockDim.x + threadIdx.x;
    if (i >= n8) return;
    int i8 = i * 8;
    int row = i8 >> lshift;
    int col = i8 & mask;
    float4 a = ((const float4*)in)[2 * i];
    float4 b = ((const float4*)in)[2 * i + 1];
    bf16x8 o;
    o[0] = (bf16_t)a.x; o[1] = (bf16_t)a.y; o[2] = (bf16_t)a.z; o[3] = (bf16_t)a.w;
    o[4] = (bf16_t)b.x; o[5] = (bf16_t)b.y; o[6] = (bf16_t)b.z; o[7] = (bf16_t)b.w;
    *(bf16x8*)&out[(size_t)row * 640 + colOff + col] = o;
}

// ---------------------------------------------------------------------------
// RMSNorm f32 in -> bf16 out (row stride ostride). One wave per row.
__global__ __launch_bounds__(256) void rmsnorm_k(const float* __restrict__ in,
                                                 const float* __restrict__ w,
                                                 bf16_t* __restrict__ out,
                                                 int ostride) {
    int wv = threadIdx.x >> 6, lane = threadIdx.x & 63;
    int row = (blockIdx.x << 2) + wv;
    const float* rp = in + (size_t)row * DMODEL + lane * 8;
    float4 v0 = *(const float4*)(rp);
    float4 v1 = *(const float4*)(rp + 4);
    float ss = v0.x*v0.x + v0.y*v0.y + v0.z*v0.z + v0.w*v0.w
             + v1.x*v1.x + v1.y*v1.y + v1.z*v1.z + v1.w*v1.w;
#pragma unroll
    for (int off = 32; off; off >>= 1) ss += __shfl_xor(ss, off, 64);
    float sc = rsqrtf(ss * (1.f / DMODEL) + 1e-6f);
    const float* wp = w + lane * 8;
    float4 w0 = *(const float4*)(wp);
    float4 w1 = *(const float4*)(wp + 4);
    bf16x8 o;
    o[0] = (bf16_t)(v0.x * sc * w0.x); o[1] = (bf16_t)(v0.y * sc * w0.y);
    o[2] = (bf16_t)(v0.z * sc * w0.z); o[3] = (bf16_t)(v0.w * sc * w0.w);
    o[4] = (bf16_t)(v1.x * sc * w1.x); o[5] = (bf16_t)(v1.y * sc * w1.y);
    o[6] = (bf16_t)(v1.z * sc * w1.z); o[7] = (bf16_t)(v1.w * sc * w1.w);
    *(bf16x8*)(out + (size_t)row * ostride + lane * 8) = o;
}

// ---------------------------------------------------------------------------
// bf16 MFMA GEMM: C[M,N] = A[M,K] @ B[N,K]^T
// Triple-buffered LDS, 2-deep prefetch, counted vmcnt, raw s_barrier.
// 1D grid with bijective XCD-chunked swizzle (grid % 8 == 0 always here).
// BM in {128, 64}; BN = 128. 256 threads, 4 waves (2M x 2N).
// EPI: 0 = f32 store, 1 = f32 +=, 2 = bf16 relu(acc)^2,
//      4 = bf16 store with fused RoPE on cols < 1024 (QKV output)
template<int BM, int EPI>
__global__ __launch_bounds__(256) void gemm_mfma(const bf16_t* __restrict__ A,
                                                 const bf16_t* __restrict__ B,
                                                 float* __restrict__ Cf,
                                                 bf16_t* __restrict__ Cb,
                                                 const float* __restrict__ cosT,
                                                 const float* __restrict__ sinT,
                                                 int M, int N, int K, int nbx) {
    constexpr int MI  = BM / 32;     // M fragments per wave (4 or 2)
    constexpr int ACH = BM / 64;     // A-staging 16B chunks per thread (2 or 1)
    __shared__ __align__(16) bf16_t As[3][BM * 32];
    __shared__ __align__(16) bf16_t Bs[3][128 * 32];
    const int tid = threadIdx.x;
    const int w = tid >> 6, lane = tid & 63;

    // bijective XCD-chunk swizzle: XCD x gets a contiguous work range
    const int nwg = (int)gridDim.x;
    const int bid = blockIdx.x;
    const int swz = (bid & 7) * (nwg >> 3) + (bid >> 3);
    const int bx = swz % nbx, by = swz / nbx;

    const int m0 = by * BM, n0 = bx * 128;
    const int wr = (w >> 1) * (BM / 2), wc = (w & 1) * 64;
    const int fr = lane & 15, fq = lane >> 4;

    f32x4 acc[MI][4] = {};

    auto stage = [&](int k0, int buf) {
#pragma unroll
        for (int c = 0; c < ACH; ++c) {
            int idx = c * 256 + tid;
            int row = idx >> 2, cs = idx & 3;
            GLD16(A + (size_t)(m0 + row) * K + k0 + cs * 8,
                  &As[buf][(size_t)(c * 256 + w * 64) * 8]);
        }
#pragma unroll
        for (int c = 0; c < 2; ++c) {
            int idx = c * 256 + tid;
            int row = idx >> 2, cs = idx & 3;
            GLD16(B + (size_t)(n0 + row) * K + k0 + cs * 8,
                  &Bs[buf][(size_t)(c * 256 + w * 64) * 8]);
        }
    };

    const int NK = K >> 5;           // always >= 16 here
    stage(0, 0);
    stage(32, 1);
    for (int k = 0; k < NK; ++k) {
        const int cur = k % 3;
        if (k + 2 < NK) {
            stage((k + 2) << 5, (k + 2) % 3);
            if constexpr (BM == 128) asm volatile("s_waitcnt vmcnt(8)" ::: "memory");
            else                     asm volatile("s_waitcnt vmcnt(6)" ::: "memory");
        } else if (k + 1 < NK) {
            if constexpr (BM == 128) asm volatile("s_waitcnt vmcnt(4)" ::: "memory");
            else                     asm volatile("s_waitcnt vmcnt(3)" ::: "memory");
        } else {
            asm volatile("s_waitcnt vmcnt(0)" ::: "memory");
        }
        __builtin_amdgcn_s_barrier();
        __builtin_amdgcn_sched_barrier(0);

        bf16x8 a[MI], b[4];
        const bf16_t* ap = &As[cur][(size_t)(wr + fr) * 32 + fq * 8];
        const bf16_t* bp = &Bs[cur][(size_t)(wc + fr) * 32 + fq * 8];
#pragma unroll
        for (int i = 0; i < MI; ++i) a[i] = *(const bf16x8*)(ap + i * 16 * 32);
#pragma unroll
        for (int j = 0; j < 4; ++j)  b[j] = *(const bf16x8*)(bp + j * 16 * 32);
#pragma unroll
        for (int i = 0; i < MI; ++i)
#pragma unroll
            for (int j = 0; j < 4; ++j)
                acc[i][j] = __builtin_amdgcn_mfma_f32_16x16x32_bf16(a[i], b[j], acc[i][j], 0, 0, 0);

        asm volatile("s_waitcnt lgkmcnt(0)" ::: "memory");
        __builtin_amdgcn_s_barrier();        // all waves done reading buf cur
        __builtin_amdgcn_sched_barrier(0);
    }

    // C/D layout: col = lane&15, row = (lane>>4)*4 + reg
    if (EPI == 4) {
        // wave's 64 cols = exactly one 64-wide head (n0, wc are 64-aligned)
        const bool qk = (n0 + wc) < 1024;   // q,k get RoPE; v plain
#pragma unroll
        for (int i = 0; i < MI; ++i) {
#pragma unroll
            for (int q = 0; q < 4; ++q) {
                int row = m0 + wr + i * 16 + fq * 4 + q;
                size_t rb = (size_t)row * N + n0 + wc;
                if (qk) {
                    int t = row & (TSEQ - 1);
#pragma unroll
                    for (int j = 0; j < 2; ++j) {
                        int d = j * 16 + fr;
                        float c = cosT[t * 32 + d];
                        float s = sinT[t * 32 + d];
                        float v1 = acc[i][j][q], v2 = acc[i][j + 2][q];
                        Cb[rb + j * 16 + fr]       = (bf16_t)(v1 * c - v2 * s);
                        Cb[rb + (j + 2) * 16 + fr] = (bf16_t)(v1 * s + v2 * c);
                    }
                } else {
#pragma unroll
                    for (int j = 0; j < 4; ++j)
                        Cb[rb + j * 16 + fr] = (bf16_t)acc[i][j][q];
                }
            }
        }
        return;
    }
#pragma unroll
    for (int i = 0; i < MI; ++i) {
        int row = m0 + wr + i * 16 + fq * 4;
#pragma unroll
        for (int j = 0; j < 4; ++j) {
            int col = n0 + wc + j * 16 + fr;
#pragma unroll
            for (int q = 0; q < 4; ++q) {
                float v = acc[i][j][q];
                size_t off = (size_t)(row + q) * N + col;
                if (EPI == 0)      Cf[off] = v;
                else if (EPI == 1) Cf[off] += v;
                else if (EPI == 2) { v = fmaxf(v, 0.f); Cb[off] = (bf16_t)(v * v); }
            }
        }
    }
}

// ---------------------------------------------------------------------------
// MFMA flash attention. Block = 4 waves = one 64-row q-block of one (b,h).
// Grid 1024, heavy q-blocks dispatched first (qb = 15 - tier); bh%8 = bid%8
// keeps each bh's K/V on one XCD's L2.
// K/V double-buffered in LDS; next tile's loads issued before this tile's
// compute; one vmcnt(0) + barrier per tile.
//   QK^T swapped:  S^T = K . Q^T  (16x16x32, K LDS chunk-XOR swizzle)
//   PV   swapped:  O^T = V^T . P^T. V^T stored as two [64][32] halves
//     (GEMM-A geometry) with 2-bit granule XOR: reads stay contiguous 16B,
//     writes spread to <=4-way.  P^T frags via uniform-index shfl + select.
__global__ __launch_bounds__(256) void attn_mfma_k(const bf16_t* __restrict__ qkvb,
                                                   bf16_t* __restrict__ outb) {
    __shared__ __align__(16) bf16_t Ks[2][64 * 64];    // [key][slot^] chunk-XOR
    __shared__ __align__(16) bf16_t VsT[2][2 * 64 * 32]; // [s][d][key32^]

    const int tid = threadIdx.x;
    const int w  = tid >> 6;
    const int ln = tid & 63;
    const int lr = ln & 15;       // q-lane
    const int lg = ln >> 4;       // lane group

    const int bid = blockIdx.x;            // 0..1023
    const int qb = 15 - (bid >> 6);        // heavy tiers first
    const int bh = bid & 63;
    const int b = bh >> 3, h = bh & 7;
    const int tq0b = qb << 6;
    const int tq0  = tq0b + w * 16;
    const int qrow = tq0 + lr;

    const bf16_t* Qg = qkvb + (size_t)b * TSEQ * 1536 + h * 64;
    const bf16_t* Kg = Qg + 512;
    const bf16_t* Vg = Qg + 1024;

    // V staging micro-tile: keys mk*4..+3, d md*4..+3
    const int mk = tid >> 4;      // 0..15
    const int md = tid & 15;      // 0..15
    const int src0 = lr + 32 * (lg & 1);   // P source lanes: src0, src0+16
    const int fsel = lg >> 1;
    const int gofs = 8 * (lg ^ ((lr >> 2) & 3));   // read granule offset (elems)

    auto KSTAGE = [&](int t0, int buf) {
#pragma unroll
        for (int ii = 0; ii < 2; ++ii) {
            const int i = w * 2 + ii;
            int key = i * 8 + (ln >> 3);
            int dc  = (ln & 7) ^ (ln >> 3);
            GLD16(Kg + (size_t)(t0 + key) * 1536 + dc * 8, &Ks[buf][i * 512]);
        }
    };
    auto VLOAD = [&](int t0, bf16x4* rv) {
#pragma unroll
        for (int i = 0; i < 4; ++i)
            rv[i] = *(const bf16x4*)(Vg + (size_t)(t0 + mk * 4 + i) * 1536 + md * 4);
    };
    auto VWRITE = [&](const bf16x4* rv, int buf) {
        const int s = mk >> 3;
#pragma unroll
        for (int j = 0; j < 4; ++j) {
            int row = md * 4 + j;
            bf16x4 wv;
            wv[0] = rv[0][j]; wv[1] = rv[1][j]; wv[2] = rv[2][j]; wv[3] = rv[3][j];
            int g = (mk & 7) ^ ((md & 3) << 1);
            *(bf16x4*)&VsT[buf][s * 2048 + row * 32 + g * 4] = wv;
        }
    };

    // Q regs (B-operand of swapped QK), prescaled by 0.125
    bf16x8 qreg[2];
    {
        const bf16_t* qp = Qg + (size_t)qrow * 1536 + lg * 8;
        qreg[0] = *(const bf16x8*)qp;
        qreg[1] = *(const bf16x8*)(qp + 32);
#pragma unroll
        for (int j = 0; j < 8; ++j) {
            qreg[0][j] = (bf16_t)((float)qreg[0][j] * 0.125f);
            qreg[1][j] = (bf16_t)((float)qreg[1][j] * 0.125f);
        }
    }

    f32x4 accO[4] = {};       // accO[dblk][r] = O[q=qrow][d=dblk*16+lg*4+r]
    float mrun = -1e30f, pl = 0.f, esf = 0.f;

    // prologue: stage tile 0 into buf 0
    {
        bf16x4 rv[4];
        KSTAGE(0, 0);
        VLOAD(0, rv);
        asm volatile("s_waitcnt vmcnt(0)" ::: "memory");
        VWRITE(rv, 0);
        asm volatile("s_waitcnt lgkmcnt(0)" ::: "memory");
        __builtin_amdgcn_s_barrier();
        __builtin_amdgcn_sched_barrier(0);
    }

    for (int t0 = 0; t0 <= tq0b; t0 += 64) {
        const int cur = (t0 >> 6) & 1;
        const bool more = t0 < tq0b;
        bf16x4 rv[4];
        if (more) {                     // issue next tile's loads early
            KSTAGE(t0 + 64, cur ^ 1);
            VLOAD(t0 + 64, rv);
        }

        // ---- QK^T (swapped): S^T[key][q]
        f32x4 sq[4] = {};
#pragma unroll
        for (int kr = 0; kr < 4; ++kr) {
            int key = kr * 16 + lr;
#pragma unroll
            for (int s = 0; s < 2; ++s) {
                int chunk = key * 8 + ((s * 4 + lg) ^ (key & 7));
                bf16x8 kf = *(const bf16x8*)&Ks[cur][chunk * 8];
                sq[kr] = __builtin_amdgcn_mfma_f32_16x16x32_bf16(kf, qreg[s], sq[kr], 0, 0, 0);
            }
        }

        // ---- online softmax; lane's q = qrow, 16 lane-local keys
        float pv[4][4];
        float tm = -1e30f;
#pragma unroll
        for (int f = 0; f < 4; ++f)
#pragma unroll
            for (int r = 0; r < 4; ++r) {
                int key = t0 + f * 16 + lg * 4 + r;
                float sv = (key <= qrow) ? sq[f][r] : -1e30f;
                pv[f][r] = sv;
                tm = fmaxf(tm, sv);
            }
        tm = fmaxf(tm, __shfl_xor(tm, 16, 64));
        tm = fmaxf(tm, __shfl_xor(tm, 32, 64));

        // defer-max (T13): only rescale when some lane's max grew by > 8
        const bool resc = __any(tm > mrun + 8.f);
        float mnew = resc ? fmaxf(mrun, tm) : mrun;
        float psum = 0.f, pd = 0.f;
        float e16[4][4];
#pragma unroll
        for (int f = 0; f < 4; ++f)
#pragma unroll
            for (int r = 0; r < 4; ++r) {
                float e = __expf(pv[f][r] - mnew);   // masked: exp(-huge)=0
                e16[f][r] = e;
                psum += e;
                int key = t0 + f * 16 + lg * 4 + r;
                pd = (key == qrow) ? e : pd;
            }
        if (resc) {
            float corr = __expf(mrun - mnew);
            mrun = mnew;
            pl  = pl  * corr + psum;
            esf = esf * corr + pd;
#pragma unroll
            for (int dblk = 0; dblk < 4; ++dblk)
#pragma unroll
                for (int r = 0; r < 4; ++r) accO[dblk][r] *= corr;
        } else {
            pl  += psum;
            esf += pd;
        }

        // ---- pack P rows to bf16 pairs (uniform register indices only)
        u32 plo[4], phi[4];
#pragma unroll
        for (int f = 0; f < 4; ++f) {
            bf16x4 t;
            t[0] = (bf16_t)e16[f][0]; t[1] = (bf16_t)e16[f][1];
            t[2] = (bf16_t)e16[f][2]; t[3] = (bf16_t)e16[f][3];
            uint2 pr = __builtin_bit_cast(uint2, t);
            plo[f] = pr.x; phi[f] = pr.y;
        }

        // ---- PV (swapped): O^T = V^T . P^T
#pragma unroll
        for (int s = 0; s < 2; ++s) {
            u32 a0 = (u32)__shfl((int)plo[s * 2],     src0,      64);
            u32 a1 = (u32)__shfl((int)phi[s * 2],     src0,      64);
            u32 a2 = (u32)__shfl((int)plo[s * 2],     src0 + 16, 64);
            u32 a3 = (u32)__shfl((int)phi[s * 2],     src0 + 16, 64);
            u32 c0 = (u32)__shfl((int)plo[s * 2 + 1], src0,      64);
            u32 c1 = (u32)__shfl((int)phi[s * 2 + 1], src0,      64);
            u32 c2 = (u32)__shfl((int)plo[s * 2 + 1], src0 + 16, 64);
            u32 c3 = (u32)__shfl((int)phi[s * 2 + 1], src0 + 16, 64);
            u32x4 bw;
            bw[0] = fsel ? c0 : a0;
            bw[1] = fsel ? c1 : a1;
            bw[2] = fsel ? c2 : a2;
            bw[3] = fsel ? c3 : a3;
            bf16x8 bfrag = __builtin_bit_cast(bf16x8, bw);
#pragma unroll
            for (int dblk = 0; dblk < 4; ++dblk) {
                bf16x8 av = *(const bf16x8*)&VsT[cur][s * 2048 + (dblk * 16 + lr) * 32 + gofs];
                accO[dblk] = __builtin_amdgcn_mfma_f32_16x16x32_bf16(av, bfrag, accO[dblk], 0, 0, 0);
            }
        }

        // ---- land next tile's V; close the tile
        if (more) {
            asm volatile("s_waitcnt vmcnt(0)" ::: "memory");
            VWRITE(rv, cur ^ 1);
            asm volatile("s_waitcnt lgkmcnt(0)" ::: "memory");
            __builtin_amdgcn_s_barrier();
            __builtin_amdgcn_sched_barrier(0);
        }
    }

    // ---- epilogue: reduce l/self-weight over lane groups, subtract, store
    pl  += __shfl_xor(pl, 16, 64);  pl  += __shfl_xor(pl, 32, 64);
    esf += __shfl_xor(esf, 16, 64); esf += __shfl_xor(esf, 32, 64);
    float rin = 1.0f / pl;
    const bf16_t* vqp = Vg + (size_t)qrow * 1536;
    bf16_t* op = outb + (size_t)(b * TSEQ + qrow) * DMODEL + h * 64;
#pragma unroll
    for (int dblk = 0; dblk < 4; ++dblk) {
        bf16x4 vq = *(const bf16x4*)(vqp + dblk * 16 + lg * 4);
        bf16x4 o4;
#pragma unroll
        for (int r = 0; r < 4; ++r)
            o4[r] = (bf16_t)((accO[dblk][r] - esf * (float)vq[r]) * rin);
        *(bf16x4*)(op + dblk * 16 + lg * 4) = o4;
    }
}

// ---------------------------------------------------------------------------
static inline void cvt(const float* in, bf16_t* out, size_t n, hipStream_t s) {
    int n8 = (int)(n / 8);
    cvt_bf16_k<<<(n8 + 255) / 256, 256, 0, s>>>(in, out, n8);
}

extern "C" void kernel_launch(void* const* d_in, const int* in_sizes, int n_in,
                              void* d_out, int out_size, void* d_ws, size_t ws_size,
                              hipStream_t stream) {
    const int*   x     = (const int*)d_in[0];
    const float* embed = (const float*)d_in[1];
    const float* Wqkv  = (const float*)d_in[2];
    const float* Wproj = (const float*)d_in[3];
    const float* n1w   = (const float*)d_in[4];
    const float* n2w   = (const float*)d_in[5];
    const float* Wfc1  = (const float*)d_in[6];
    const float* Wfc2  = (const float*)d_in[7];
    const float* normf = (const float*)d_in[8];
    const float* bge   = (const float*)d_in[9];
    const float* bgp   = (const float*)d_in[10];
    float* out = (float*)d_out;

    // workspace layout (~103 MB)
    float* ws   = (float*)d_ws;
    float* cosT = ws;                            // 32768
    float* sinT = cosT + 32768;                  // 32768
    float* h    = sinT + 32768;                  // 8192*512 f32
    bf16_t* qkvb = (bf16_t*)(h + (size_t)NROW * DMODEL);  // 8192*1536 bf16
    bf16_t* ub   = qkvb;                         // alias: qkvb dead when fc1 runs
    bf16_t* Afu  = qkvb;                         // alias: fused logits A (8192x640)
    bf16_t* xn   = qkvb + (size_t)NROW * 1536;
    bf16_t* atb  = xn  + (size_t)NROW * DMODEL;
    bf16_t* wqb  = atb + (size_t)NROW * DMODEL;
    bf16_t* wpb  = wqb + (size_t)LAYERS * 3 * DMODEL * DMODEL;
    bf16_t* w1b  = wpb + (size_t)LAYERS * DMODEL * DMODEL;
    bf16_t* w2b  = w1b + (size_t)LAYERS * HIDDEN * DMODEL;
    bf16_t* bfu  = w2b + (size_t)LAYERS * DMODEL * HIDDEN;  // 1024*640 fused B

    rope_table_k<<<128, 256, 0, stream>>>(cosT, sinT);
    embed_gather_k<<<NROW, 128, 0, stream>>>(x, embed, h);

    cvt(Wqkv,  wqb,  (size_t)LAYERS * 3 * DMODEL * DMODEL, stream);
    cvt(Wproj, wpb,  (size_t)LAYERS * DMODEL * DMODEL, stream);
    cvt(Wfc1,  w1b,  (size_t)LAYERS * HIDDEN * DMODEL, stream);
    cvt(Wfc2,  w2b,  (size_t)LAYERS * DMODEL * HIDDEN, stream);
    // fused logits B: [1024 rows][640] = [embed | bg_proj]
    cvt_pad_k<<<(65536 + 255) / 256, 256, 0, stream>>>(embed, bfu, 65536, 9, 511, 0);
    cvt_pad_k<<<(16384 + 255) / 256, 256, 0, stream>>>(bgp,   bfu, 16384, 7, 127, 512);

    for (int i = 0; i < LAYERS; ++i) {
        rmsnorm_k<<<NROW / 4, 256, 0, stream>>>(h, n1w + i * DMODEL, xn, DMODEL);
        gemm_mfma<128, 4><<<768, 256, 0, stream>>>(
            xn, wqb + (size_t)i * 3 * DMODEL * DMODEL, nullptr, qkvb,
            cosT, sinT, NROW, 3 * DMODEL, DMODEL, 12);
        attn_mfma_k<<<1024, 256, 0, stream>>>(qkvb, atb);
        gemm_mfma<64, 1><<<512, 256, 0, stream>>>(
            atb, wpb + (size_t)i * DMODEL * DMODEL, h, nullptr,
            nullptr, nullptr, NROW, DMODEL, DMODEL, 4);
        rmsnorm_k<<<NROW / 4, 256, 0, stream>>>(h, n2w + i * DMODEL, xn, DMODEL);
        gemm_mfma<128, 2><<<768, 256, 0, stream>>>(
            xn, w1b + (size_t)i * HIDDEN * DMODEL, nullptr, ub,
            nullptr, nullptr, NROW, HIDDEN, DMODEL, 12);
        gemm_mfma<64, 1><<<512, 256, 0, stream>>>(
            ub, w2b + (size_t)i * DMODEL * HIDDEN, h, nullptr,
            nullptr, nullptr, NROW, DMODEL, HIDDEN, 4);
    }

    // fused logits: [xn | bga] @ [embed | bgp]^T, K = 640
    rmsnorm_k<<<NROW / 4, 256, 0, stream>>>(h, normf, Afu, 640);
    bg_gather_k<<<NROW, 128, 0, stream>>>(x, bge, Afu);
    gemm_mfma<64, 0><<<1024, 256, 0, stream>>>(
        Afu, bfu, out, nullptr, nullptr, nullptr, NROW, 1024, 640, 8);
}